// Round 1
// baseline (483.157 us; speedup 1.0000x reference)
//
#include <hip/hip_runtime.h>
#include <cmath>
#include <cstring>

#define HH 224
#define WW 224
#define CROP 160
#define CI 32
#define CJ 32
#define NCH 384                 // 128*3
#define CH_STRIDE (HH*WW)       // 50176
#define CROP_STRIDE (CROP*CROP) // 25600
#define CHB 16                  // channels per block in warp_kernel

struct AugParams {
  float a, b, c, d, e, f, g, h;   // perspective coeffs
  float cosT, sinT;               // rotation
};

// ---------------------------------------------------------------------------
// Bicubic (Keys a=-0.5) axis weights, matching jax.image.resize:
//   sample_f = (o+0.5)*(160/224) - 0.5 ; taps floor-1..floor+2 ;
//   out-of-range taps dropped ; weights renormalized to sum 1.
// ---------------------------------------------------------------------------
__device__ __forceinline__ void axis_weights(int o, float w[4], int id[4]) {
  float s = (o + 0.5f) * (160.0f / 224.0f) - 0.5f;
  int base = (int)floorf(s) - 1;
  float sum = 0.0f;
#pragma unroll
  for (int t = 0; t < 4; ++t) {
    int ii = base + t;
    float dd = fabsf(s - (float)ii);
    float kw;
    if (dd < 1.0f)      kw = ((1.5f * dd - 2.5f) * dd) * dd + 1.0f;
    else if (dd < 2.0f) kw = ((-0.5f * dd + 2.5f) * dd - 4.0f) * dd + 2.0f;
    else                kw = 0.0f;
    if (ii < 0 || ii > CROP - 1) kw = 0.0f;
    w[t] = kw;
    sum += kw;
    id[t] = min(max(ii, 0), CROP - 1);
  }
  float inv = 1.0f / sum;
#pragma unroll
  for (int t = 0; t < 4; ++t) w[t] *= inv;
}

__global__ void table_kernel(float4* __restrict__ wt, int4* __restrict__ it) {
  int o = blockIdx.x * blockDim.x + threadIdx.x;
  if (o >= HH) return;
  float w[4]; int id[4];
  axis_weights(o, w, id);
  wt[o] = make_float4(w[0], w[1], w[2], w[3]);
  it[o] = make_int4(id[0], id[1], id[2], id[3]);
}

// ---------------------------------------------------------------------------
// Compute the 16 combined (offset, weight) taps for crop pixel (i,j):
// rotation bilinear (4 neighbors) x perspective bilinear (4 taps each),
// both with zero-padding validity, exactly matching the reference.
// ---------------------------------------------------------------------------
__device__ __forceinline__ void make_taps(int i, int j, const AugParams P,
                                          int offs[16], float wts[16]) {
  const float cx = (WW - 1) * 0.5f, cy = (HH - 1) * 0.5f;
  float xr = (float)(j + CJ), yr = (float)(i + CI);
  float dx = xr - cx, dy = yr - cy;
  float rx = cx + P.cosT * dx + P.sinT * dy;
  float ry = cy - P.sinT * dx + P.cosT * dy;
  float x0f = floorf(rx), y0f = floorf(ry);
  int x0 = (int)x0f, y0 = (int)y0f;
  float wx1 = rx - x0f, wy1 = ry - y0f;
  float rwx[2] = {1.0f - wx1, wx1};
  float rwy[2] = {1.0f - wy1, wy1};
  int k = 0;
#pragma unroll
  for (int ny = 0; ny < 2; ++ny) {
#pragma unroll
    for (int nx = 0; nx < 2; ++nx) {
      int yn = y0 + ny, xn = x0 + nx;
      bool vn = (xn >= 0 && xn <= WW - 1 && yn >= 0 && yn <= HH - 1);
      float wn = rwy[ny] * rwx[nx] * (vn ? 1.0f : 0.0f);
      float xo = (float)xn, yo = (float)yn;
      float den = P.g * xo + P.h * yo + 1.0f;
      float inv = 1.0f / den;
      float px = (P.a * xo + P.b * yo + P.c) * inv;
      float py = (P.d * xo + P.e * yo + P.f) * inv;
      float px0f = floorf(px), py0f = floorf(py);
      int px0 = (int)px0f, py0 = (int)py0f;
      float pwx1 = px - px0f, pwy1 = py - py0f;
      float pwx[2] = {1.0f - pwx1, pwx1};
      float pwy[2] = {1.0f - pwy1, pwy1};
#pragma unroll
      for (int ty = 0; ty < 2; ++ty) {
#pragma unroll
        for (int tx = 0; tx < 2; ++tx) {
          int yt = py0 + ty, xt = px0 + tx;
          bool vt = (xt >= 0 && xt <= WW - 1 && yt >= 0 && yt <= HH - 1);
          int yc = min(max(yt, 0), HH - 1);
          int xc = min(max(xt, 0), WW - 1);
          offs[k] = yc * WW + xc;
          wts[k] = wn * pwy[ty] * pwx[tx] * (vt ? 1.0f : 0.0f);
          ++k;
        }
      }
    }
  }
}

__device__ __forceinline__ float preproc(float v, float nv) {
  float p = (v + 0.45f * nv) * 1.1f;
  return fminf(fmaxf(p, 0.0f), 1.0f);
}

// ---------------------------------------------------------------------------
// Kernel 1: crop[ch][i][j] = rotated(perspective(preproc(x)))[i+32][j+32]
// One thread per crop pixel; taps computed once, reused across CHB channels.
// ---------------------------------------------------------------------------
__global__ __launch_bounds__(256) void warp_kernel(
    const float* __restrict__ xin, const float* __restrict__ nin,
    float* __restrict__ crop, AugParams P) {
  int pix = blockIdx.x * 256 + threadIdx.x;   // 0..25599, grid.x = 100
  int i = pix / CROP;
  int j = pix - i * CROP;

  int offs[16];
  float wts[16];
  make_taps(i, j, P, offs, wts);

  int ch0 = blockIdx.y * CHB;
#pragma unroll 2
  for (int ch = ch0; ch < ch0 + CHB; ++ch) {
    const float* xb = xin + (size_t)ch * CH_STRIDE;
    const float* nb = nin + (size_t)ch * CH_STRIDE;
    float acc = 0.0f;
#pragma unroll
    for (int k = 0; k < 16; ++k) {
      float v = xb[offs[k]];
      float nv = nb[offs[k]];
      acc = fmaf(wts[k], preproc(v, nv), acc);
    }
    crop[(size_t)ch * CROP_STRIDE + pix] = acc;
  }
}

// ---------------------------------------------------------------------------
// Kernel 2: separable bicubic 160 -> 224 using the precomputed table.
// ---------------------------------------------------------------------------
__global__ __launch_bounds__(256) void resize_kernel(
    const float* __restrict__ crop, const float4* __restrict__ wt,
    const int4* __restrict__ it, float* __restrict__ out, int total) {
  int stride = gridDim.x * blockDim.x;
  for (int idx = blockIdx.x * blockDim.x + threadIdx.x; idx < total; idx += stride) {
    int xo = idx % WW;
    int t2 = idx / WW;
    int yo = t2 % HH;
    int ch = t2 / HH;
    float4 wx = wt[xo]; int4 ix = it[xo];
    float4 wy = wt[yo]; int4 iy = it[yo];
    const float* cb = crop + (size_t)ch * CROP_STRIDE;
    const float* r0 = cb + iy.x * CROP;
    const float* r1 = cb + iy.y * CROP;
    const float* r2 = cb + iy.z * CROP;
    const float* r3 = cb + iy.w * CROP;
    float s0 = wx.x * r0[ix.x] + wx.y * r0[ix.y] + wx.z * r0[ix.z] + wx.w * r0[ix.w];
    float s1 = wx.x * r1[ix.x] + wx.y * r1[ix.y] + wx.z * r1[ix.z] + wx.w * r1[ix.w];
    float s2 = wx.x * r2[ix.x] + wx.y * r2[ix.y] + wx.z * r2[ix.z] + wx.w * r2[ix.w];
    float s3 = wx.x * r3[ix.x] + wx.y * r3[ix.y] + wx.z * r3[ix.z] + wx.w * r3[ix.w];
    out[idx] = wy.x * s0 + wy.y * s1 + wy.z * s2 + wy.w * s3;
  }
}

// ---------------------------------------------------------------------------
// Fallback: fully fused (used only if d_ws is too small). Correct but slow.
// ---------------------------------------------------------------------------
__device__ float crop_val(const float* __restrict__ xb, const float* __restrict__ nb,
                          int i, int j, AugParams P) {
  int offs[16]; float wts[16];
  make_taps(i, j, P, offs, wts);
  float acc = 0.0f;
#pragma unroll
  for (int k = 0; k < 16; ++k)
    acc = fmaf(wts[k], preproc(xb[offs[k]], nb[offs[k]]), acc);
  return acc;
}

__global__ __launch_bounds__(256) void fused_fallback_kernel(
    const float* __restrict__ xin, const float* __restrict__ nin,
    float* __restrict__ out, AugParams P, int total) {
  int stride = gridDim.x * blockDim.x;
  for (int idx = blockIdx.x * blockDim.x + threadIdx.x; idx < total; idx += stride) {
    int xo = idx % WW;
    int t2 = idx / WW;
    int yo = t2 % HH;
    int ch = t2 / HH;
    float wxa[4]; int ixa[4]; axis_weights(xo, wxa, ixa);
    float wya[4]; int iya[4]; axis_weights(yo, wya, iya);
    const float* xb = xin + (size_t)ch * CH_STRIDE;
    const float* nb = nin + (size_t)ch * CH_STRIDE;
    float acc = 0.0f;
#pragma unroll
    for (int ty = 0; ty < 4; ++ty) {
#pragma unroll
      for (int tx = 0; tx < 4; ++tx) {
        acc += wya[ty] * wxa[tx] * crop_val(xb, nb, iya[ty], ixa[tx], P);
      }
    }
    out[idx] = acc;
  }
}

// ---------------------------------------------------------------------------
// Host: solve the 8x8 perspective system (double, Gauss-Jordan w/ pivoting).
// ---------------------------------------------------------------------------
static void solve_coeffs(double C[8]) {
  const double sp[4][2] = {{0, 0}, {223, 0}, {223, 223}, {0, 223}};
  const double ep[4][2] = {{30, 20}, {200, 25}, {210, 200}, {15, 190}};
  double A[8][9];
  for (int k = 0; k < 4; ++k) {
    double xi = sp[k][0], yi = sp[k][1], xo = ep[k][0], yo = ep[k][1];
    double r0[9] = {xo, yo, 1, 0, 0, 0, -xo * xi, -yo * xi, xi};
    double r1[9] = {0, 0, 0, xo, yo, 1, -xo * yi, -yo * yi, yi};
    std::memcpy(A[2 * k], r0, sizeof r0);
    std::memcpy(A[2 * k + 1], r1, sizeof r1);
  }
  for (int col = 0; col < 8; ++col) {
    int piv = col;
    for (int r = col + 1; r < 8; ++r)
      if (std::fabs(A[r][col]) > std::fabs(A[piv][col])) piv = r;
    if (piv != col)
      for (int cc = 0; cc < 9; ++cc) { double t = A[col][cc]; A[col][cc] = A[piv][cc]; A[piv][cc] = t; }
    double p = A[col][col];
    for (int r = 0; r < 8; ++r) {
      if (r == col) continue;
      double fmul = A[r][col] / p;
      for (int cc = col; cc < 9; ++cc) A[r][cc] -= fmul * A[col][cc];
    }
  }
  for (int r = 0; r < 8; ++r) C[r] = A[r][8] / A[r][r];
}

extern "C" void kernel_launch(void* const* d_in, const int* in_sizes, int n_in,
                              void* d_out, int out_size, void* d_ws, size_t ws_size,
                              hipStream_t stream) {
  const float* xin = (const float*)d_in[0];
  const float* nin = (const float*)d_in[1];
  float* out = (float*)d_out;

  double C[8];
  solve_coeffs(C);
  AugParams P;
  P.a = (float)C[0]; P.b = (float)C[1]; P.c = (float)C[2]; P.d = (float)C[3];
  P.e = (float)C[4]; P.f = (float)C[5]; P.g = (float)C[6]; P.h = (float)C[7];
  double t = 10.0 * M_PI / 180.0;
  P.cosT = (float)std::cos(t);
  P.sinT = (float)std::sin(t);

  const int total = NCH * HH * WW;                 // 19,267,584
  const size_t tbl_w_off = 0;                      // float4[224] = 3584 B
  const size_t tbl_i_off = 3584;                   // int4[224]   = 3584 B
  const size_t crop_off = 8192;
  const size_t need = crop_off + (size_t)NCH * CROP_STRIDE * sizeof(float);

  if (ws_size >= need) {
    float4* wt = (float4*)((char*)d_ws + tbl_w_off);
    int4*   it = (int4*)((char*)d_ws + tbl_i_off);
    float* crop = (float*)((char*)d_ws + crop_off);

    hipLaunchKernelGGL(table_kernel, dim3(1), dim3(256), 0, stream, wt, it);
    dim3 g1(CROP_STRIDE / 256, NCH / CHB);         // (100, 24)
    hipLaunchKernelGGL(warp_kernel, g1, dim3(256), 0, stream, xin, nin, crop, P);
    hipLaunchKernelGGL(resize_kernel, dim3(2048), dim3(256), 0, stream,
                       crop, wt, it, out, total);
  } else {
    hipLaunchKernelGGL(fused_fallback_kernel, dim3(2048), dim3(256), 0, stream,
                       xin, nin, out, P, total);
  }
}

// Round 2
// 191.543 us; speedup vs baseline: 2.5224x; 2.5224x over previous
//
#include <hip/hip_runtime.h>
#include <cmath>
#include <cstring>

#define HH 224
#define WW 224
#define CROP 160
#define CI 32
#define CJ 32
#define NCH 384                 // 128*3
#define CH_STRIDE (HH*WW)       // 50176
#define CROP_STRIDE (CROP*CROP) // 25600
#define TILE 32
#define NTIL 5                  // 5x5 tiles of 32x32 over the 160x160 crop
#define BCAP 84
#define BCAP2 (BCAP*BCAP)       // 7056 floats = 28224 B LDS

struct AugParams {
  float a, b, c, d, e, f, g, h;   // perspective coeffs
  float cosT, sinT;               // rotation
};

// ---------------------------------------------------------------------------
// Bicubic (Keys a=-0.5) axis weights, matching jax.image.resize.
// ---------------------------------------------------------------------------
__device__ __forceinline__ void axis_weights(int o, float w[4], int id[4]) {
  float s = (o + 0.5f) * (160.0f / 224.0f) - 0.5f;
  int base = (int)floorf(s) - 1;
  float sum = 0.0f;
#pragma unroll
  for (int t = 0; t < 4; ++t) {
    int ii = base + t;
    float dd = fabsf(s - (float)ii);
    float kw;
    if (dd < 1.0f)      kw = ((1.5f * dd - 2.5f) * dd) * dd + 1.0f;
    else if (dd < 2.0f) kw = ((-0.5f * dd + 2.5f) * dd - 4.0f) * dd + 2.0f;
    else                kw = 0.0f;
    if (ii < 0 || ii > CROP - 1) kw = 0.0f;
    w[t] = kw;
    sum += kw;
    id[t] = min(max(ii, 0), CROP - 1);
  }
  float inv = 1.0f / sum;
#pragma unroll
  for (int t = 0; t < 4; ++t) w[t] *= inv;
}

__global__ void table_kernel(float4* __restrict__ wt, int4* __restrict__ it) {
  int o = blockIdx.x * blockDim.x + threadIdx.x;
  if (o >= HH) return;
  float w[4]; int id[4];
  axis_weights(o, w, id);
  wt[o] = make_float4(w[0], w[1], w[2], w[3]);
  it[o] = make_int4(id[0], id[1], id[2], id[3]);
}

// ---------------------------------------------------------------------------
// 16 combined taps (global x/y coords + weights) for crop pixel (i,j):
// rotation bilinear (4 neighbors) x perspective bilinear (4 taps each).
// ---------------------------------------------------------------------------
__device__ __forceinline__ void make_taps(int i, int j, const AugParams P,
                                          int txs[16], int tys[16], float wts[16]) {
  const float cx = (WW - 1) * 0.5f, cy = (HH - 1) * 0.5f;
  float xr = (float)(j + CJ), yr = (float)(i + CI);
  float dx = xr - cx, dy = yr - cy;
  float rx = cx + P.cosT * dx + P.sinT * dy;
  float ry = cy - P.sinT * dx + P.cosT * dy;
  float x0f = floorf(rx), y0f = floorf(ry);
  int x0 = (int)x0f, y0 = (int)y0f;
  float wx1 = rx - x0f, wy1 = ry - y0f;
  float rwx[2] = {1.0f - wx1, wx1};
  float rwy[2] = {1.0f - wy1, wy1};
  int k = 0;
#pragma unroll
  for (int ny = 0; ny < 2; ++ny) {
#pragma unroll
    for (int nx = 0; nx < 2; ++nx) {
      int yn = y0 + ny, xn = x0 + nx;
      bool vn = (xn >= 0 && xn <= WW - 1 && yn >= 0 && yn <= HH - 1);
      float wn = rwy[ny] * rwx[nx] * (vn ? 1.0f : 0.0f);
      float xo = (float)xn, yo = (float)yn;
      float inv = 1.0f / (P.g * xo + P.h * yo + 1.0f);
      float px = (P.a * xo + P.b * yo + P.c) * inv;
      float py = (P.d * xo + P.e * yo + P.f) * inv;
      float px0f = floorf(px), py0f = floorf(py);
      int px0 = (int)px0f, py0 = (int)py0f;
      float pwx1 = px - px0f, pwy1 = py - py0f;
      float pwx[2] = {1.0f - pwx1, pwx1};
      float pwy[2] = {1.0f - pwy1, pwy1};
#pragma unroll
      for (int ty = 0; ty < 2; ++ty) {
#pragma unroll
        for (int tx = 0; tx < 2; ++tx) {
          int yt = py0 + ty, xt = px0 + tx;
          bool vt = (xt >= 0 && xt <= WW - 1 && yt >= 0 && yt <= HH - 1);
          tys[k] = min(max(yt, 0), HH - 1);
          txs[k] = min(max(xt, 0), WW - 1);
          wts[k] = wn * pwy[ty] * pwx[tx] * (vt ? 1.0f : 0.0f);
          ++k;
        }
      }
    }
  }
}

__device__ __forceinline__ float preproc(float v, float nv) {
  float p = (v + 0.45f * nv) * 1.1f;
  return fminf(fmaxf(p, 0.0f), 1.0f);
}

// ---------------------------------------------------------------------------
// Kernel 1 (tiled): block = (one 32x32 crop tile) x (one channel).
// Stage the exact source bbox (preprocessed) into LDS with coalesced loads,
// then gather the 16 taps per pixel from LDS.
// ---------------------------------------------------------------------------
__global__ __launch_bounds__(256) void warp_tiled_kernel(
    const float* __restrict__ xin, const float* __restrict__ nin,
    float* __restrict__ crop, AugParams P) {
  __shared__ float s_img[BCAP2];
  int tile = blockIdx.x;                 // 0..24
  int ch   = blockIdx.y;                 // 0..383
  int i0 = (tile / NTIL) * TILE;
  int j0 = (tile % NTIL) * TILE;

  // ---- wave-uniform exact bbox via corner transforms ----
  const float cx = (WW - 1) * 0.5f, cy = (HH - 1) * 0.5f;
  float rxmin = 1e30f, rxmax = -1e30f, rymin = 1e30f, rymax = -1e30f;
#pragma unroll
  for (int c = 0; c < 4; ++c) {
    float xr = (float)(j0 + CJ + ((c & 1) ? TILE - 1 : 0));
    float yr = (float)(i0 + CI + ((c & 2) ? TILE - 1 : 0));
    float dx = xr - cx, dy = yr - cy;
    float rx = cx + P.cosT * dx + P.sinT * dy;
    float ry = cy - P.sinT * dx + P.cosT * dy;
    rxmin = fminf(rxmin, rx); rxmax = fmaxf(rxmax, rx);
    rymin = fminf(rymin, ry); rymax = fmaxf(rymax, ry);
  }
  // integer rotation-neighbor range (floor .. floor+1)
  float xnlo = floorf(rxmin), xnhi = floorf(rxmax) + 1.0f;
  float ynlo = floorf(rymin), ynhi = floorf(rymax) + 1.0f;
  // perspective of that rect: extremes at corners (Mobius monotone per edge)
  float pxmin = 1e30f, pxmax = -1e30f, pymin = 1e30f, pymax = -1e30f;
#pragma unroll
  for (int c = 0; c < 4; ++c) {
    float xo = (c & 1) ? xnhi : xnlo;
    float yo = (c & 2) ? ynhi : ynlo;
    float inv = 1.0f / (P.g * xo + P.h * yo + 1.0f);
    float px = (P.a * xo + P.b * yo + P.c) * inv;
    float py = (P.d * xo + P.e * yo + P.f) * inv;
    pxmin = fminf(pxmin, px); pxmax = fmaxf(pxmax, px);
    pymin = fminf(pymin, py); pymax = fmaxf(pymax, py);
  }
  int bx0 = max(0, (int)floorf(pxmin));
  int bx1 = min(WW - 1, (int)floorf(pxmax) + 1);
  int by0 = max(0, (int)floorf(pymin));
  int by1 = min(HH - 1, (int)floorf(pymax) + 1);
  int bw = bx1 - bx0 + 1;
  int bh = by1 - by0 + 1;
  bool use_lds = (bw * bh <= BCAP2);

  const float* xb = xin + (size_t)ch * CH_STRIDE;
  const float* nb = nin + (size_t)ch * CH_STRIDE;
  float* cb = crop + (size_t)ch * CROP_STRIDE;

  if (use_lds) {
    int total = bw * bh;
    for (int idx = threadIdx.x; idx < total; idx += 256) {
      int ly = (int)((unsigned)idx / (unsigned)bw);
      int lx = idx - ly * bw;
      int g = (by0 + ly) * WW + bx0 + lx;
      s_img[idx] = preproc(xb[g], nb[g]);
    }
    __syncthreads();
#pragma unroll
    for (int k = 0; k < 4; ++k) {
      int p = threadIdx.x + k * 256;          // 0..1023 within tile
      int i = i0 + (p >> 5);
      int j = j0 + (p & 31);
      int txs[16], tys[16]; float wts[16];
      make_taps(i, j, P, txs, tys, wts);
      float acc = 0.0f;
#pragma unroll
      for (int t = 0; t < 16; ++t) {
        int ly = min(max(tys[t] - by0, 0), bh - 1);
        int lx = min(max(txs[t] - bx0, 0), bw - 1);
        acc = fmaf(wts[t], s_img[ly * bw + lx], acc);
      }
      cb[i * CROP + j] = acc;
    }
  } else {
    // safety fallback: global gather (never expected for TILE=32, BCAP=84)
#pragma unroll
    for (int k = 0; k < 4; ++k) {
      int p = threadIdx.x + k * 256;
      int i = i0 + (p >> 5);
      int j = j0 + (p & 31);
      int txs[16], tys[16]; float wts[16];
      make_taps(i, j, P, txs, tys, wts);
      float acc = 0.0f;
#pragma unroll
      for (int t = 0; t < 16; ++t) {
        int g = tys[t] * WW + txs[t];
        acc = fmaf(wts[t], preproc(xb[g], nb[g]), acc);
      }
      cb[i * CROP + j] = acc;
    }
  }
}

// ---------------------------------------------------------------------------
// Kernel 2: separable bicubic 160 -> 224 using the precomputed table.
// ---------------------------------------------------------------------------
__global__ __launch_bounds__(256) void resize_kernel(
    const float* __restrict__ crop, const float4* __restrict__ wt,
    const int4* __restrict__ it, float* __restrict__ out, int total) {
  int stride = gridDim.x * blockDim.x;
  for (int idx = blockIdx.x * blockDim.x + threadIdx.x; idx < total; idx += stride) {
    int xo = idx % WW;
    int t2 = idx / WW;
    int yo = t2 % HH;
    int ch = t2 / HH;
    float4 wx = wt[xo]; int4 ix = it[xo];
    float4 wy = wt[yo]; int4 iy = it[yo];
    const float* cb = crop + (size_t)ch * CROP_STRIDE;
    const float* r0 = cb + iy.x * CROP;
    const float* r1 = cb + iy.y * CROP;
    const float* r2 = cb + iy.z * CROP;
    const float* r3 = cb + iy.w * CROP;
    float s0 = wx.x * r0[ix.x] + wx.y * r0[ix.y] + wx.z * r0[ix.z] + wx.w * r0[ix.w];
    float s1 = wx.x * r1[ix.x] + wx.y * r1[ix.y] + wx.z * r1[ix.z] + wx.w * r1[ix.w];
    float s2 = wx.x * r2[ix.x] + wx.y * r2[ix.y] + wx.z * r2[ix.z] + wx.w * r2[ix.w];
    float s3 = wx.x * r3[ix.x] + wx.y * r3[ix.y] + wx.z * r3[ix.z] + wx.w * r3[ix.w];
    out[idx] = wy.x * s0 + wy.y * s1 + wy.z * s2 + wy.w * s3;
  }
}

// ---------------------------------------------------------------------------
// Fallback: fully fused (used only if d_ws is too small).
// ---------------------------------------------------------------------------
__device__ float crop_val(const float* __restrict__ xb, const float* __restrict__ nb,
                          int i, int j, AugParams P) {
  int txs[16], tys[16]; float wts[16];
  make_taps(i, j, P, txs, tys, wts);
  float acc = 0.0f;
#pragma unroll
  for (int t = 0; t < 16; ++t)
    acc = fmaf(wts[t], preproc(xb[tys[t] * WW + txs[t]], nb[tys[t] * WW + txs[t]]), acc);
  return acc;
}

__global__ __launch_bounds__(256) void fused_fallback_kernel(
    const float* __restrict__ xin, const float* __restrict__ nin,
    float* __restrict__ out, AugParams P, int total) {
  int stride = gridDim.x * blockDim.x;
  for (int idx = blockIdx.x * blockDim.x + threadIdx.x; idx < total; idx += stride) {
    int xo = idx % WW;
    int t2 = idx / WW;
    int yo = t2 % HH;
    int ch = t2 / HH;
    float wxa[4]; int ixa[4]; axis_weights(xo, wxa, ixa);
    float wya[4]; int iya[4]; axis_weights(yo, wya, iya);
    const float* xb = xin + (size_t)ch * CH_STRIDE;
    const float* nb = nin + (size_t)ch * CH_STRIDE;
    float acc = 0.0f;
#pragma unroll
    for (int ty = 0; ty < 4; ++ty)
#pragma unroll
      for (int tx = 0; tx < 4; ++tx)
        acc += wya[ty] * wxa[tx] * crop_val(xb, nb, iya[ty], ixa[tx], P);
    out[idx] = acc;
  }
}

// ---------------------------------------------------------------------------
// Host: solve the 8x8 perspective system (double, Gauss-Jordan w/ pivoting).
// ---------------------------------------------------------------------------
static void solve_coeffs(double C[8]) {
  const double sp[4][2] = {{0, 0}, {223, 0}, {223, 223}, {0, 223}};
  const double ep[4][2] = {{30, 20}, {200, 25}, {210, 200}, {15, 190}};
  double A[8][9];
  for (int k = 0; k < 4; ++k) {
    double xi = sp[k][0], yi = sp[k][1], xo = ep[k][0], yo = ep[k][1];
    double r0[9] = {xo, yo, 1, 0, 0, 0, -xo * xi, -yo * xi, xi};
    double r1[9] = {0, 0, 0, xo, yo, 1, -xo * yi, -yo * yi, yi};
    std::memcpy(A[2 * k], r0, sizeof r0);
    std::memcpy(A[2 * k + 1], r1, sizeof r1);
  }
  for (int col = 0; col < 8; ++col) {
    int piv = col;
    for (int r = col + 1; r < 8; ++r)
      if (std::fabs(A[r][col]) > std::fabs(A[piv][col])) piv = r;
    if (piv != col)
      for (int cc = 0; cc < 9; ++cc) { double t = A[col][cc]; A[col][cc] = A[piv][cc]; A[piv][cc] = t; }
    double p = A[col][col];
    for (int r = 0; r < 8; ++r) {
      if (r == col) continue;
      double fmul = A[r][col] / p;
      for (int cc = col; cc < 9; ++cc) A[r][cc] -= fmul * A[col][cc];
    }
  }
  for (int r = 0; r < 8; ++r) C[r] = A[r][8] / A[r][r];
}

extern "C" void kernel_launch(void* const* d_in, const int* in_sizes, int n_in,
                              void* d_out, int out_size, void* d_ws, size_t ws_size,
                              hipStream_t stream) {
  const float* xin = (const float*)d_in[0];
  const float* nin = (const float*)d_in[1];
  float* out = (float*)d_out;

  double C[8];
  solve_coeffs(C);
  AugParams P;
  P.a = (float)C[0]; P.b = (float)C[1]; P.c = (float)C[2]; P.d = (float)C[3];
  P.e = (float)C[4]; P.f = (float)C[5]; P.g = (float)C[6]; P.h = (float)C[7];
  double t = 10.0 * M_PI / 180.0;
  P.cosT = (float)std::cos(t);
  P.sinT = (float)std::sin(t);

  const int total = NCH * HH * WW;                 // 19,267,584
  const size_t tbl_w_off = 0;                      // float4[224] = 3584 B
  const size_t tbl_i_off = 3584;                   // int4[224]   = 3584 B
  const size_t crop_off = 8192;
  const size_t need = crop_off + (size_t)NCH * CROP_STRIDE * sizeof(float);

  if (ws_size >= need) {
    float4* wt = (float4*)((char*)d_ws + tbl_w_off);
    int4*   it = (int4*)((char*)d_ws + tbl_i_off);
    float* crop = (float*)((char*)d_ws + crop_off);

    hipLaunchKernelGGL(table_kernel, dim3(1), dim3(256), 0, stream, wt, it);
    dim3 g1(NTIL * NTIL, NCH);                     // (25, 384)
    hipLaunchKernelGGL(warp_tiled_kernel, g1, dim3(256), 0, stream, xin, nin, crop, P);
    hipLaunchKernelGGL(resize_kernel, dim3(2048), dim3(256), 0, stream,
                       crop, wt, it, out, total);
  } else {
    hipLaunchKernelGGL(fused_fallback_kernel, dim3(2048), dim3(256), 0, stream,
                       xin, nin, out, P, total);
  }
}

// Round 3
// 142.957 us; speedup vs baseline: 3.3797x; 1.3399x over previous
//
#include <hip/hip_runtime.h>
#include <cmath>
#include <cstring>

#define HH 224
#define WW 224
#define CROP 160
#define CI 32
#define CJ 32
#define NCH 384                 // 128*3
#define CH_STRIDE (HH*WW)       // 50176
#define CROP_STRIDE (CROP*CROP) // 25600
#define TILE 32
#define NTIL 5                  // 5x5 tiles of 32x32 over the 160x160 crop
#define GCH 16                  // channels per warp-block
#define LDSH 64                 // max bbox rows
#define LDSTR 65                // LDS row stride (floats) -> conflict-free

struct AugParams {
  float a, b, c, d, e, f, g, h;   // perspective coeffs
  float cosT, sinT;               // rotation
};

// ---------------------------------------------------------------------------
// Bicubic (Keys a=-0.5) axis weights, matching jax.image.resize.
// ---------------------------------------------------------------------------
__device__ __forceinline__ void axis_weights(int o, float w[4], int id[4]) {
  float s = (o + 0.5f) * (160.0f / 224.0f) - 0.5f;
  int base = (int)floorf(s) - 1;
  float sum = 0.0f;
#pragma unroll
  for (int t = 0; t < 4; ++t) {
    int ii = base + t;
    float dd = fabsf(s - (float)ii);
    float kw;
    if (dd < 1.0f)      kw = ((1.5f * dd - 2.5f) * dd) * dd + 1.0f;
    else if (dd < 2.0f) kw = ((-0.5f * dd + 2.5f) * dd - 4.0f) * dd + 2.0f;
    else                kw = 0.0f;
    if (ii < 0 || ii > CROP - 1) kw = 0.0f;
    w[t] = kw;
    sum += kw;
    id[t] = min(max(ii, 0), CROP - 1);
  }
  float inv = 1.0f / sum;
#pragma unroll
  for (int t = 0; t < 4; ++t) w[t] *= inv;
}

__global__ void table_kernel(float4* __restrict__ wt, int4* __restrict__ it) {
  int o = blockIdx.x * blockDim.x + threadIdx.x;
  if (o >= HH) return;
  float w[4]; int id[4];
  axis_weights(o, w, id);
  wt[o] = make_float4(w[0], w[1], w[2], w[3]);
  it[o] = make_int4(id[0], id[1], id[2], id[3]);
}

// ---------------------------------------------------------------------------
// 16 combined taps (global x/y coords + weights) for crop pixel (i,j).
// ---------------------------------------------------------------------------
__device__ __forceinline__ void make_taps(int i, int j, const AugParams P,
                                          int txs[16], int tys[16], float wts[16]) {
  const float cx = (WW - 1) * 0.5f, cy = (HH - 1) * 0.5f;
  float xr = (float)(j + CJ), yr = (float)(i + CI);
  float dx = xr - cx, dy = yr - cy;
  float rx = cx + P.cosT * dx + P.sinT * dy;
  float ry = cy - P.sinT * dx + P.cosT * dy;
  float x0f = floorf(rx), y0f = floorf(ry);
  int x0 = (int)x0f, y0 = (int)y0f;
  float wx1 = rx - x0f, wy1 = ry - y0f;
  float rwx[2] = {1.0f - wx1, wx1};
  float rwy[2] = {1.0f - wy1, wy1};
  int k = 0;
#pragma unroll
  for (int ny = 0; ny < 2; ++ny) {
#pragma unroll
    for (int nx = 0; nx < 2; ++nx) {
      int yn = y0 + ny, xn = x0 + nx;
      bool vn = (xn >= 0 && xn <= WW - 1 && yn >= 0 && yn <= HH - 1);
      float wn = rwy[ny] * rwx[nx] * (vn ? 1.0f : 0.0f);
      float xo = (float)xn, yo = (float)yn;
      float inv = 1.0f / (P.g * xo + P.h * yo + 1.0f);
      float px = (P.a * xo + P.b * yo + P.c) * inv;
      float py = (P.d * xo + P.e * yo + P.f) * inv;
      float px0f = floorf(px), py0f = floorf(py);
      int px0 = (int)px0f, py0 = (int)py0f;
      float pwx1 = px - px0f, pwy1 = py - py0f;
      float pwx[2] = {1.0f - pwx1, pwx1};
      float pwy[2] = {1.0f - pwy1, pwy1};
#pragma unroll
      for (int ty = 0; ty < 2; ++ty) {
#pragma unroll
        for (int tx = 0; tx < 2; ++tx) {
          int yt = py0 + ty, xt = px0 + tx;
          bool vt = (xt >= 0 && xt <= WW - 1 && yt >= 0 && yt <= HH - 1);
          tys[k] = min(max(yt, 0), HH - 1);
          txs[k] = min(max(xt, 0), WW - 1);
          wts[k] = wn * pwy[ty] * pwx[tx] * (vt ? 1.0f : 0.0f);
          ++k;
        }
      }
    }
  }
}

__device__ __forceinline__ float preproc(float v, float nv) {
  float p = (v + 0.45f * nv) * 1.1f;
  return fminf(fmaxf(p, 0.0f), 1.0f);
}

// ---------------------------------------------------------------------------
// Kernel 1: block = 1024 threads = one 32x32 crop tile x 16 channels.
// Taps computed ONCE per pixel (channel-invariant), converted to fixed-stride
// LDS offsets once. Per-channel: async-split staging (issue loads early,
// ds_write after gathers) with double-buffered LDS; one sync per channel.
// ---------------------------------------------------------------------------
__global__ __launch_bounds__(1024, 1) void warp_tiled_kernel(
    const float* __restrict__ xin, const float* __restrict__ nin,
    float* __restrict__ crop, AugParams P) {
  __shared__ float s_img[2][LDSH * LDSTR];
  int tile = blockIdx.x;                 // 0..24
  int ch0  = blockIdx.y * GCH;           // 0..383 step 16
  int i0 = (tile / NTIL) * TILE;
  int j0 = (tile % NTIL) * TILE;

  // ---- wave-uniform exact bbox via corner transforms ----
  const float cx = (WW - 1) * 0.5f, cy = (HH - 1) * 0.5f;
  float rxmin = 1e30f, rxmax = -1e30f, rymin = 1e30f, rymax = -1e30f;
#pragma unroll
  for (int c = 0; c < 4; ++c) {
    float xr = (float)(j0 + CJ + ((c & 1) ? TILE - 1 : 0));
    float yr = (float)(i0 + CI + ((c & 2) ? TILE - 1 : 0));
    float dx = xr - cx, dy = yr - cy;
    float rx = cx + P.cosT * dx + P.sinT * dy;
    float ry = cy - P.sinT * dx + P.cosT * dy;
    rxmin = fminf(rxmin, rx); rxmax = fmaxf(rxmax, rx);
    rymin = fminf(rymin, ry); rymax = fmaxf(rymax, ry);
  }
  float xnlo = floorf(rxmin), xnhi = floorf(rxmax) + 1.0f;
  float ynlo = floorf(rymin), ynhi = floorf(rymax) + 1.0f;
  float pxmin = 1e30f, pxmax = -1e30f, pymin = 1e30f, pymax = -1e30f;
#pragma unroll
  for (int c = 0; c < 4; ++c) {
    float xo = (c & 1) ? xnhi : xnlo;
    float yo = (c & 2) ? ynhi : ynlo;
    float inv = 1.0f / (P.g * xo + P.h * yo + 1.0f);
    float px = (P.a * xo + P.b * yo + P.c) * inv;
    float py = (P.d * xo + P.e * yo + P.f) * inv;
    pxmin = fminf(pxmin, px); pxmax = fmaxf(pxmax, px);
    pymin = fminf(pymin, py); pymax = fmaxf(pymax, py);
  }
  int bx0 = max(0, (int)floorf(pxmin));
  int bx1 = min(WW - 1, (int)floorf(pxmax) + 1);
  int by0 = max(0, (int)floorf(pymin));
  int by1 = min(HH - 1, (int)floorf(pymax) + 1);
  int bw = bx1 - bx0 + 1;
  int bh = by1 - by0 + 1;
  bool use_lds = (bw <= LDSH && bh <= LDSH);

  int tid = threadIdx.x;
  int i = i0 + (tid >> 5);
  int j = j0 + (tid & 31);
  int txs[16], tys[16]; float wts[16];
  make_taps(i, j, P, txs, tys, wts);
  int opix = i * CROP + j;

  if (use_lds) {
    int lofs[16];
#pragma unroll
    for (int t = 0; t < 16; ++t) {
      int ly = min(max(tys[t] - by0, 0), bh - 1);
      int lx = min(max(txs[t] - bx0, 0), bw - 1);
      lofs[t] = ly * LDSTR + lx;
    }
    int nslots = bh * 64;

    // prologue: stage channel ch0 into buffer 0
    {
      const float* xb = xin + (size_t)ch0 * CH_STRIDE;
      const float* nb = nin + (size_t)ch0 * CH_STRIDE;
#pragma unroll
      for (int k = 0; k < 4; ++k) {
        int s = tid + k * 1024;
        if (s < nslots) {
          int ly = s >> 6, lx = s & 63;
          if (lx < bw) {
            int g = (by0 + ly) * WW + bx0 + lx;
            s_img[0][ly * LDSTR + lx] = preproc(xb[g], nb[g]);
          }
        }
      }
      __syncthreads();
    }

    int buf = 0;
    for (int cc = 0; cc < GCH; ++cc) {
      int ch = ch0 + cc;
      // issue next channel's global loads early (latency hides under gathers)
      float xv[4], nv[4];
      bool more = (cc < GCH - 1);
      if (more) {
        const float* xb = xin + (size_t)(ch + 1) * CH_STRIDE;
        const float* nb = nin + (size_t)(ch + 1) * CH_STRIDE;
#pragma unroll
        for (int k = 0; k < 4; ++k) {
          int s = tid + k * 1024;
          if (s < nslots) {
            int ly = s >> 6, lx = s & 63;
            if (lx < bw) {
              int g = (by0 + ly) * WW + bx0 + lx;
              xv[k] = xb[g];
              nv[k] = nb[g];
            }
          }
        }
      }
      // gather current channel from LDS
      float acc = 0.0f;
#pragma unroll
      for (int t = 0; t < 16; ++t)
        acc = fmaf(wts[t], s_img[buf][lofs[t]], acc);
      crop[(size_t)ch * CROP_STRIDE + opix] = acc;
      // write staged next channel to the other buffer
      if (more) {
#pragma unroll
        for (int k = 0; k < 4; ++k) {
          int s = tid + k * 1024;
          if (s < nslots) {
            int ly = s >> 6, lx = s & 63;
            if (lx < bw)
              s_img[buf ^ 1][ly * LDSTR + lx] = preproc(xv[k], nv[k]);
          }
        }
      }
      __syncthreads();
      buf ^= 1;
    }
  } else {
    // safety fallback: global gather (not expected for TILE=32)
    for (int cc = 0; cc < GCH; ++cc) {
      int ch = ch0 + cc;
      const float* xb = xin + (size_t)ch * CH_STRIDE;
      const float* nb = nin + (size_t)ch * CH_STRIDE;
      float acc = 0.0f;
#pragma unroll
      for (int t = 0; t < 16; ++t) {
        int g = tys[t] * WW + txs[t];
        acc = fmaf(wts[t], preproc(xb[g], nb[g]), acc);
      }
      crop[(size_t)ch * CROP_STRIDE + opix] = acc;
    }
  }
}

// ---------------------------------------------------------------------------
// Kernel 2: block = one (channel, output row). Load the 4 needed crop rows
// into LDS (coalesced), vertically combine into v[160], then 4-tap horizontal.
// ---------------------------------------------------------------------------
__global__ __launch_bounds__(256) void resize_rows_kernel(
    const float* __restrict__ crop, const float4* __restrict__ wt,
    const int4* __restrict__ it, float* __restrict__ out) {
  __shared__ float rows[4 * CROP];
  __shared__ float v[CROP];
  int bx = blockIdx.x;
  int yo = (bx & 7) * 28 + (bx >> 3);    // XCD-friendly: adjacent rows same L2
  int ch = blockIdx.y;
  float4 wy = wt[yo]; int4 iy = it[yo];
  const float* cb = crop + (size_t)ch * CROP_STRIDE;
  int tid = threadIdx.x;

  for (int s = tid; s < 4 * CROP; s += 256) {
    int r = s / CROP;
    int x = s - r * CROP;
    int ry = (r == 0) ? iy.x : ((r == 1) ? iy.y : ((r == 2) ? iy.z : iy.w));
    rows[s] = cb[ry * CROP + x];
  }
  __syncthreads();
  if (tid < CROP) {
    v[tid] = wy.x * rows[tid] + wy.y * rows[CROP + tid] +
             wy.z * rows[2 * CROP + tid] + wy.w * rows[3 * CROP + tid];
  }
  __syncthreads();
  if (tid < WW) {
    float4 wx = wt[tid]; int4 ix = it[tid];
    float o = wx.x * v[ix.x] + wx.y * v[ix.y] + wx.z * v[ix.z] + wx.w * v[ix.w];
    out[((size_t)ch * HH + yo) * WW + tid] = o;
  }
}

// ---------------------------------------------------------------------------
// Fallback: fully fused (used only if d_ws is too small).
// ---------------------------------------------------------------------------
__device__ float crop_val(const float* __restrict__ xb, const float* __restrict__ nb,
                          int i, int j, AugParams P) {
  int txs[16], tys[16]; float wts[16];
  make_taps(i, j, P, txs, tys, wts);
  float acc = 0.0f;
#pragma unroll
  for (int t = 0; t < 16; ++t)
    acc = fmaf(wts[t], preproc(xb[tys[t] * WW + txs[t]], nb[tys[t] * WW + txs[t]]), acc);
  return acc;
}

__global__ __launch_bounds__(256) void fused_fallback_kernel(
    const float* __restrict__ xin, const float* __restrict__ nin,
    float* __restrict__ out, AugParams P, int total) {
  int stride = gridDim.x * blockDim.x;
  for (int idx = blockIdx.x * blockDim.x + threadIdx.x; idx < total; idx += stride) {
    int xo = idx % WW;
    int t2 = idx / WW;
    int yo = t2 % HH;
    int ch = t2 / HH;
    float wxa[4]; int ixa[4]; axis_weights(xo, wxa, ixa);
    float wya[4]; int iya[4]; axis_weights(yo, wya, iya);
    const float* xb = xin + (size_t)ch * CH_STRIDE;
    const float* nb = nin + (size_t)ch * CH_STRIDE;
    float acc = 0.0f;
#pragma unroll
    for (int ty = 0; ty < 4; ++ty)
#pragma unroll
      for (int tx = 0; tx < 4; ++tx)
        acc += wya[ty] * wxa[tx] * crop_val(xb, nb, iya[ty], ixa[tx], P);
    out[idx] = acc;
  }
}

// ---------------------------------------------------------------------------
// Host: solve the 8x8 perspective system (double, Gauss-Jordan w/ pivoting).
// ---------------------------------------------------------------------------
static void solve_coeffs(double C[8]) {
  const double sp[4][2] = {{0, 0}, {223, 0}, {223, 223}, {0, 223}};
  const double ep[4][2] = {{30, 20}, {200, 25}, {210, 200}, {15, 190}};
  double A[8][9];
  for (int k = 0; k < 4; ++k) {
    double xi = sp[k][0], yi = sp[k][1], xo = ep[k][0], yo = ep[k][1];
    double r0[9] = {xo, yo, 1, 0, 0, 0, -xo * xi, -yo * xi, xi};
    double r1[9] = {0, 0, 0, xo, yo, 1, -xo * yi, -yo * yi, yi};
    std::memcpy(A[2 * k], r0, sizeof r0);
    std::memcpy(A[2 * k + 1], r1, sizeof r1);
  }
  for (int col = 0; col < 8; ++col) {
    int piv = col;
    for (int r = col + 1; r < 8; ++r)
      if (std::fabs(A[r][col]) > std::fabs(A[piv][col])) piv = r;
    if (piv != col)
      for (int cc = 0; cc < 9; ++cc) { double t = A[col][cc]; A[col][cc] = A[piv][cc]; A[piv][cc] = t; }
    double p = A[col][col];
    for (int r = 0; r < 8; ++r) {
      if (r == col) continue;
      double fmul = A[r][col] / p;
      for (int cc = col; cc < 9; ++cc) A[r][cc] -= fmul * A[col][cc];
    }
  }
  for (int r = 0; r < 8; ++r) C[r] = A[r][8] / A[r][r];
}

extern "C" void kernel_launch(void* const* d_in, const int* in_sizes, int n_in,
                              void* d_out, int out_size, void* d_ws, size_t ws_size,
                              hipStream_t stream) {
  const float* xin = (const float*)d_in[0];
  const float* nin = (const float*)d_in[1];
  float* out = (float*)d_out;

  double C[8];
  solve_coeffs(C);
  AugParams P;
  P.a = (float)C[0]; P.b = (float)C[1]; P.c = (float)C[2]; P.d = (float)C[3];
  P.e = (float)C[4]; P.f = (float)C[5]; P.g = (float)C[6]; P.h = (float)C[7];
  double t = 10.0 * M_PI / 180.0;
  P.cosT = (float)std::cos(t);
  P.sinT = (float)std::sin(t);

  const int total = NCH * HH * WW;                 // 19,267,584
  const size_t tbl_w_off = 0;                      // float4[224] = 3584 B
  const size_t tbl_i_off = 3584;                   // int4[224]   = 3584 B
  const size_t crop_off = 8192;
  const size_t need = crop_off + (size_t)NCH * CROP_STRIDE * sizeof(float);

  if (ws_size >= need) {
    float4* wt = (float4*)((char*)d_ws + tbl_w_off);
    int4*   it = (int4*)((char*)d_ws + tbl_i_off);
    float* crop = (float*)((char*)d_ws + crop_off);

    hipLaunchKernelGGL(table_kernel, dim3(1), dim3(256), 0, stream, wt, it);
    dim3 g1(NTIL * NTIL, NCH / GCH);               // (25, 24)
    hipLaunchKernelGGL(warp_tiled_kernel, g1, dim3(1024), 0, stream, xin, nin, crop, P);
    dim3 g2(HH, NCH);                              // (224, 384)
    hipLaunchKernelGGL(resize_rows_kernel, g2, dim3(256), 0, stream, crop, wt, it, out);
  } else {
    hipLaunchKernelGGL(fused_fallback_kernel, dim3(2048), dim3(256), 0, stream,
                       xin, nin, out, P, total);
  }
}

// Round 4
// 141.363 us; speedup vs baseline: 3.4179x; 1.0113x over previous
//
#include <hip/hip_runtime.h>
#include <cmath>
#include <cstring>

#define HH 224
#define WW 224
#define CROP 160
#define CI 32
#define CJ 32
#define NCH 384                 // 128*3
#define CH_STRIDE (HH*WW)       // 50176
#define CROP_STRIDE (CROP*CROP) // 25600
#define TILE 16
#define NTIL 10                 // 10x10 tiles of 16x16 over the 160x160 crop
#define GCH 8                   // channels per warp-block
#define BMAXH 33                // max bbox rows (cap)
#define BMAXW 35                // max bbox cols (cap)
#define LROWS 35                // phys rows  (1 pad top + 33 + 1 pad bottom)
#define LSTR  37                // phys cols / stride (1 pad left + 35 + 1)
#define LWORDS (LROWS*LSTR)     // 1295 floats per buffer

struct AugParams {
  float a, b, c, d, e, f, g, h;   // perspective coeffs
  float cosT, sinT;               // rotation
};

// ---------------------------------------------------------------------------
// Bicubic (Keys a=-0.5) axis weights, matching jax.image.resize.
// ---------------------------------------------------------------------------
__device__ __forceinline__ void axis_weights(int o, float w[4], int id[4]) {
  float s = (o + 0.5f) * (160.0f / 224.0f) - 0.5f;
  int base = (int)floorf(s) - 1;
  float sum = 0.0f;
#pragma unroll
  for (int t = 0; t < 4; ++t) {
    int ii = base + t;
    float dd = fabsf(s - (float)ii);
    float kw;
    if (dd < 1.0f)      kw = ((1.5f * dd - 2.5f) * dd) * dd + 1.0f;
    else if (dd < 2.0f) kw = ((-0.5f * dd + 2.5f) * dd - 4.0f) * dd + 2.0f;
    else                kw = 0.0f;
    if (ii < 0 || ii > CROP - 1) kw = 0.0f;
    w[t] = kw;
    sum += kw;
    id[t] = min(max(ii, 0), CROP - 1);
  }
  float inv = 1.0f / sum;
#pragma unroll
  for (int t = 0; t < 4; ++t) w[t] *= inv;
}

__global__ void table_kernel(float4* __restrict__ wt, int4* __restrict__ it) {
  int o = blockIdx.x * blockDim.x + threadIdx.x;
  if (o >= HH) return;
  float w[4]; int id[4];
  axis_weights(o, w, id);
  wt[o] = make_float4(w[0], w[1], w[2], w[3]);
  it[o] = make_int4(id[0], id[1], id[2], id[3]);
}

// ---------------------------------------------------------------------------
// 16 combined taps (global coords, clamped) — used by fallback paths only.
// ---------------------------------------------------------------------------
__device__ __forceinline__ void make_taps(int i, int j, const AugParams P,
                                          int txs[16], int tys[16], float wts[16]) {
  const float cx = (WW - 1) * 0.5f, cy = (HH - 1) * 0.5f;
  float xr = (float)(j + CJ), yr = (float)(i + CI);
  float dx = xr - cx, dy = yr - cy;
  float rx = cx + P.cosT * dx + P.sinT * dy;
  float ry = cy - P.sinT * dx + P.cosT * dy;
  float x0f = floorf(rx), y0f = floorf(ry);
  int x0 = (int)x0f, y0 = (int)y0f;
  float wx1 = rx - x0f, wy1 = ry - y0f;
  float rwx[2] = {1.0f - wx1, wx1};
  float rwy[2] = {1.0f - wy1, wy1};
  int k = 0;
#pragma unroll
  for (int ny = 0; ny < 2; ++ny) {
#pragma unroll
    for (int nx = 0; nx < 2; ++nx) {
      int yn = y0 + ny, xn = x0 + nx;
      bool vn = (xn >= 0 && xn <= WW - 1 && yn >= 0 && yn <= HH - 1);
      float wn = rwy[ny] * rwx[nx] * (vn ? 1.0f : 0.0f);
      float xo = (float)xn, yo = (float)yn;
      float inv = 1.0f / (P.g * xo + P.h * yo + 1.0f);
      float px = (P.a * xo + P.b * yo + P.c) * inv;
      float py = (P.d * xo + P.e * yo + P.f) * inv;
      float px0f = floorf(px), py0f = floorf(py);
      int px0 = (int)px0f, py0 = (int)py0f;
      float pwx1 = px - px0f, pwy1 = py - py0f;
      float pwx[2] = {1.0f - pwx1, pwx1};
      float pwy[2] = {1.0f - pwy1, pwy1};
#pragma unroll
      for (int ty = 0; ty < 2; ++ty) {
#pragma unroll
        for (int tx = 0; tx < 2; ++tx) {
          int yt = py0 + ty, xt = px0 + tx;
          bool vt = (xt >= 0 && xt <= WW - 1 && yt >= 0 && yt <= HH - 1);
          tys[k] = min(max(yt, 0), HH - 1);
          txs[k] = min(max(xt, 0), WW - 1);
          wts[k] = wn * pwy[ty] * pwx[tx] * (vt ? 1.0f : 0.0f);
          ++k;
        }
      }
    }
  }
}

// ---------------------------------------------------------------------------
// 4 patch origins (LDS phys offsets) + 16 weights for crop pixel (i,j).
// Each rotation neighbor's 2x2 perspective patch reads p, p+1, p+LSTR,
// p+LSTR+1. Any tap whose weight is nonzero lies inside the bbox, so its
// origin index is exact; weight-0 taps may read any in-bounds (finite) slot.
// ---------------------------------------------------------------------------
__device__ __forceinline__ void make_patches(int i, int j, const AugParams P,
                                             int by0, int bx0, int bh, int bw,
                                             int pofs[4], float wts[16]) {
  const float cx = (WW - 1) * 0.5f, cy = (HH - 1) * 0.5f;
  float xr = (float)(j + CJ), yr = (float)(i + CI);
  float dx = xr - cx, dy = yr - cy;
  float rx = cx + P.cosT * dx + P.sinT * dy;
  float ry = cy - P.sinT * dx + P.cosT * dy;
  float x0f = floorf(rx), y0f = floorf(ry);
  int x0 = (int)x0f, y0 = (int)y0f;
  float wx1 = rx - x0f, wy1 = ry - y0f;
  float rwx[2] = {1.0f - wx1, wx1};
  float rwy[2] = {1.0f - wy1, wy1};
  int n = 0;
#pragma unroll
  for (int ny = 0; ny < 2; ++ny) {
#pragma unroll
    for (int nx = 0; nx < 2; ++nx) {
      int yn = y0 + ny, xn = x0 + nx;
      bool vn = (xn >= 0 && xn <= WW - 1 && yn >= 0 && yn <= HH - 1);
      float wn = rwy[ny] * rwx[nx] * (vn ? 1.0f : 0.0f);
      float xo = (float)xn, yo = (float)yn;
      float inv = 1.0f / (P.g * xo + P.h * yo + 1.0f);
      float px = (P.a * xo + P.b * yo + P.c) * inv;
      float py = (P.d * xo + P.e * yo + P.f) * inv;
      float px0f = floorf(px), py0f = floorf(py);
      int px0 = (int)px0f, py0 = (int)py0f;
      float pwx1 = px - px0f, pwy1 = py - py0f;
      float pwx[2] = {1.0f - pwx1, pwx1};
      float pwy[2] = {1.0f - pwy1, pwy1};
#pragma unroll
      for (int ty = 0; ty < 2; ++ty) {
#pragma unroll
        for (int tx = 0; tx < 2; ++tx) {
          int yt = py0 + ty, xt = px0 + tx;
          bool vt = (xt >= 0 && xt <= WW - 1 && yt >= 0 && yt <= HH - 1);
          wts[n * 4 + ty * 2 + tx] = wn * pwy[ty] * pwx[tx] * (vt ? 1.0f : 0.0f);
        }
      }
      int ly = py0 - by0;
      int lx = px0 - bx0;
      if (ly < -1 || ly > bh - 1) ly = 0;   // only possible when weights are 0
      if (lx < -1 || lx > bw - 1) lx = 0;
      pofs[n] = (ly + 1) * LSTR + (lx + 1);
      ++n;
    }
  }
}

__device__ __forceinline__ float preproc(float v, float nv) {
  float p = (v + 0.45f * nv) * 1.1f;
  return fminf(fmaxf(p, 0.0f), 1.0f);
}

// ---------------------------------------------------------------------------
// Kernel 1: block = 256 threads = one 16x16 crop tile x 8 channels.
// Patch origins + weights computed once per pixel, reused across channels.
// Double-buffered LDS, async-split staging, one barrier per channel.
// ---------------------------------------------------------------------------
__global__ __launch_bounds__(256) void warp_tiled_kernel(
    const float* __restrict__ xin, const float* __restrict__ nin,
    float* __restrict__ crop, AugParams P) {
  __shared__ float s_img[2][LWORDS];
  int tile = blockIdx.x;                 // 0..99
  int ch0  = blockIdx.y * GCH;
  int i0 = (tile / NTIL) * TILE;
  int j0 = (tile % NTIL) * TILE;

  // ---- wave-uniform exact bbox via corner transforms ----
  const float cx = (WW - 1) * 0.5f, cy = (HH - 1) * 0.5f;
  float rxmin = 1e30f, rxmax = -1e30f, rymin = 1e30f, rymax = -1e30f;
#pragma unroll
  for (int c = 0; c < 4; ++c) {
    float xr = (float)(j0 + CJ + ((c & 1) ? TILE - 1 : 0));
    float yr = (float)(i0 + CI + ((c & 2) ? TILE - 1 : 0));
    float dx = xr - cx, dy = yr - cy;
    float rx = cx + P.cosT * dx + P.sinT * dy;
    float ry = cy - P.sinT * dx + P.cosT * dy;
    rxmin = fminf(rxmin, rx); rxmax = fmaxf(rxmax, rx);
    rymin = fminf(rymin, ry); rymax = fmaxf(rymax, ry);
  }
  float xnlo = floorf(rxmin), xnhi = floorf(rxmax) + 1.0f;
  float ynlo = floorf(rymin), ynhi = floorf(rymax) + 1.0f;
  float pxmin = 1e30f, pxmax = -1e30f, pymin = 1e30f, pymax = -1e30f;
#pragma unroll
  for (int c = 0; c < 4; ++c) {
    float xo = (c & 1) ? xnhi : xnlo;
    float yo = (c & 2) ? ynhi : ynlo;
    float inv = 1.0f / (P.g * xo + P.h * yo + 1.0f);
    float px = (P.a * xo + P.b * yo + P.c) * inv;
    float py = (P.d * xo + P.e * yo + P.f) * inv;
    pxmin = fminf(pxmin, px); pxmax = fmaxf(pxmax, px);
    pymin = fminf(pymin, py); pymax = fmaxf(pymax, py);
  }
  int bx0 = max(0, (int)floorf(pxmin));
  int bx1 = min(WW - 1, (int)floorf(pxmax) + 1);
  int by0 = max(0, (int)floorf(pymin));
  int by1 = min(HH - 1, (int)floorf(pymax) + 1);
  int bw = bx1 - bx0 + 1;
  int bh = by1 - by0 + 1;
  bool use_lds = (bw <= BMAXW && bh <= BMAXH);

  int tid = threadIdx.x;
  int i = i0 + (tid >> 4);
  int j = j0 + (tid & 15);
  int opix = i * CROP + j;

  if (use_lds) {
    int pofs[4]; float wts[16];
    make_patches(i, j, P, by0, bx0, bh, bw, pofs, wts);

    // zero both buffers (pads + any unwritten slots stay 0 across channels)
    for (int s = tid; s < 2 * LWORDS; s += 256)
      ((float*)s_img)[s] = 0.0f;
    __syncthreads();

    // prologue: stage channel ch0 into buffer 0
    {
      const float* xb = xin + (size_t)ch0 * CH_STRIDE;
      const float* nb = nin + (size_t)ch0 * CH_STRIDE;
      int r = tid >> 5, c = tid & 31;
#pragma unroll
      for (int rr = 0; rr < 5; ++rr) {
        int rcur = r + rr * 8;
        if (rcur < bh && c < bw) {
          int g = (by0 + rcur) * WW + bx0 + c;
          s_img[0][(rcur + 1) * LSTR + (c + 1)] = preproc(xb[g], nb[g]);
        }
      }
      if (bw > 32) {
        int r2 = tid >> 2, c2 = 32 + (tid & 3);
        if (r2 < bh && c2 < bw) {
          int g = (by0 + r2) * WW + bx0 + c2;
          s_img[0][(r2 + 1) * LSTR + (c2 + 1)] = preproc(xb[g], nb[g]);
        }
      }
      __syncthreads();
    }

    int buf = 0;
    int r = tid >> 5, c = tid & 31;
    int r2 = tid >> 2, c2 = 32 + (tid & 3);
    for (int cc = 0; cc < GCH; ++cc) {
      int ch = ch0 + cc;
      bool more = (cc < GCH - 1);
      // issue next channel's loads early (latency hides under the gathers)
      float xv[5], nv[5], xe = 0.0f, ne = 0.0f;
      if (more) {
        const float* xb = xin + (size_t)(ch + 1) * CH_STRIDE;
        const float* nb = nin + (size_t)(ch + 1) * CH_STRIDE;
#pragma unroll
        for (int rr = 0; rr < 5; ++rr) {
          int rcur = r + rr * 8;
          if (rcur < bh && c < bw) {
            int g = (by0 + rcur) * WW + bx0 + c;
            xv[rr] = xb[g]; nv[rr] = nb[g];
          }
        }
        if (bw > 32 && r2 < bh && c2 < bw) {
          int g = (by0 + r2) * WW + bx0 + c2;
          xe = xb[g]; ne = nb[g];
        }
      }
      // gather current channel from LDS (2x ds_read2_b32 per neighbor)
      const float* sb = s_img[buf];
      float acc = 0.0f;
#pragma unroll
      for (int n = 0; n < 4; ++n) {
        int p = pofs[n];
        float v00 = sb[p],        v01 = sb[p + 1];
        float v10 = sb[p + LSTR], v11 = sb[p + LSTR + 1];
        acc = fmaf(wts[n * 4 + 0], v00, acc);
        acc = fmaf(wts[n * 4 + 1], v01, acc);
        acc = fmaf(wts[n * 4 + 2], v10, acc);
        acc = fmaf(wts[n * 4 + 3], v11, acc);
      }
      crop[(size_t)ch * CROP_STRIDE + opix] = acc;
      // write staged next channel into the other buffer
      if (more) {
        float* sw = s_img[buf ^ 1];
#pragma unroll
        for (int rr = 0; rr < 5; ++rr) {
          int rcur = r + rr * 8;
          if (rcur < bh && c < bw)
            sw[(rcur + 1) * LSTR + (c + 1)] = preproc(xv[rr], nv[rr]);
        }
        if (bw > 32 && r2 < bh && c2 < bw)
          sw[(r2 + 1) * LSTR + (c2 + 1)] = preproc(xe, ne);
      }
      __syncthreads();
      buf ^= 1;
    }
  } else {
    // safety fallback: global gather (not expected with these caps)
    int txs[16], tys[16]; float wts[16];
    make_taps(i, j, P, txs, tys, wts);
    for (int cc = 0; cc < GCH; ++cc) {
      int ch = ch0 + cc;
      const float* xb = xin + (size_t)ch * CH_STRIDE;
      const float* nb = nin + (size_t)ch * CH_STRIDE;
      float acc = 0.0f;
#pragma unroll
      for (int t = 0; t < 16; ++t) {
        int g = tys[t] * WW + txs[t];
        acc = fmaf(wts[t], preproc(xb[g], nb[g]), acc);
      }
      crop[(size_t)ch * CROP_STRIDE + opix] = acc;
    }
  }
}

// ---------------------------------------------------------------------------
// Kernel 2: block = 28 output rows x 224 cols of one channel (grid 8 x 384).
// Phase 1: horizontal bicubic pass into LDS H[25][224]; phase 2: vertical
// 4-tap pass, fully coalesced output.
// ---------------------------------------------------------------------------
#define STRIPROWS 28
#define HROWS 25
__global__ __launch_bounds__(256) void resize_strips_kernel(
    const float* __restrict__ crop, const float4* __restrict__ wt,
    const int4* __restrict__ it, float* __restrict__ out) {
  __shared__ float hbuf[HROWS * WW];
  int s = blockIdx.x;                    // 0..7
  int ch = blockIdx.y;                   // 0..383
  int r0 = max(0, s * 20 - 2);
  const float* cb = crop + (size_t)ch * CROP_STRIDE;
  int tid = threadIdx.x;

  for (int e = tid; e < HROWS * WW; e += 256) {
    int r = e / WW;
    int xo = e - r * WW;
    int cr = min(r0 + r, CROP - 1);
    float4 wx = wt[xo]; int4 ix = it[xo];
    const float* row = cb + cr * CROP;
    hbuf[e] = wx.x * row[ix.x] + wx.y * row[ix.y] +
              wx.z * row[ix.z] + wx.w * row[ix.w];
  }
  __syncthreads();
  for (int e = tid; e < STRIPROWS * WW; e += 256) {
    int yl = e / WW;
    int xo = e - yl * WW;
    int yo = s * STRIPROWS + yl;
    float4 wy = wt[yo]; int4 iy = it[yo];
    float o = wy.x * hbuf[(iy.x - r0) * WW + xo] +
              wy.y * hbuf[(iy.y - r0) * WW + xo] +
              wy.z * hbuf[(iy.z - r0) * WW + xo] +
              wy.w * hbuf[(iy.w - r0) * WW + xo];
    out[((size_t)ch * HH + yo) * WW + xo] = o;
  }
}

// ---------------------------------------------------------------------------
// Fallback: fully fused (used only if d_ws is too small).
// ---------------------------------------------------------------------------
__device__ float crop_val(const float* __restrict__ xb, const float* __restrict__ nb,
                          int i, int j, AugParams P) {
  int txs[16], tys[16]; float wts[16];
  make_taps(i, j, P, txs, tys, wts);
  float acc = 0.0f;
#pragma unroll
  for (int t = 0; t < 16; ++t)
    acc = fmaf(wts[t], preproc(xb[tys[t] * WW + txs[t]], nb[tys[t] * WW + txs[t]]), acc);
  return acc;
}

__global__ __launch_bounds__(256) void fused_fallback_kernel(
    const float* __restrict__ xin, const float* __restrict__ nin,
    float* __restrict__ out, AugParams P, int total) {
  int stride = gridDim.x * blockDim.x;
  for (int idx = blockIdx.x * blockDim.x + threadIdx.x; idx < total; idx += stride) {
    int xo = idx % WW;
    int t2 = idx / WW;
    int yo = t2 % HH;
    int ch = t2 / HH;
    float wxa[4]; int ixa[4]; axis_weights(xo, wxa, ixa);
    float wya[4]; int iya[4]; axis_weights(yo, wya, iya);
    const float* xb = xin + (size_t)ch * CH_STRIDE;
    const float* nb = nin + (size_t)ch * CH_STRIDE;
    float acc = 0.0f;
#pragma unroll
    for (int ty = 0; ty < 4; ++ty)
#pragma unroll
      for (int tx = 0; tx < 4; ++tx)
        acc += wya[ty] * wxa[tx] * crop_val(xb, nb, iya[ty], ixa[tx], P);
    out[idx] = acc;
  }
}

// ---------------------------------------------------------------------------
// Host: solve the 8x8 perspective system (double, Gauss-Jordan w/ pivoting).
// ---------------------------------------------------------------------------
static void solve_coeffs(double C[8]) {
  const double sp[4][2] = {{0, 0}, {223, 0}, {223, 223}, {0, 223}};
  const double ep[4][2] = {{30, 20}, {200, 25}, {210, 200}, {15, 190}};
  double A[8][9];
  for (int k = 0; k < 4; ++k) {
    double xi = sp[k][0], yi = sp[k][1], xo = ep[k][0], yo = ep[k][1];
    double r0[9] = {xo, yo, 1, 0, 0, 0, -xo * xi, -yo * xi, xi};
    double r1[9] = {0, 0, 0, xo, yo, 1, -xo * yi, -yo * yi, yi};
    std::memcpy(A[2 * k], r0, sizeof r0);
    std::memcpy(A[2 * k + 1], r1, sizeof r1);
  }
  for (int col = 0; col < 8; ++col) {
    int piv = col;
    for (int r = col + 1; r < 8; ++r)
      if (std::fabs(A[r][col]) > std::fabs(A[piv][col])) piv = r;
    if (piv != col)
      for (int cc = 0; cc < 9; ++cc) { double t = A[col][cc]; A[col][cc] = A[piv][cc]; A[piv][cc] = t; }
    double p = A[col][col];
    for (int r = 0; r < 8; ++r) {
      if (r == col) continue;
      double fmul = A[r][col] / p;
      for (int cc = col; cc < 9; ++cc) A[r][cc] -= fmul * A[col][cc];
    }
  }
  for (int r = 0; r < 8; ++r) C[r] = A[r][8] / A[r][r];
}

extern "C" void kernel_launch(void* const* d_in, const int* in_sizes, int n_in,
                              void* d_out, int out_size, void* d_ws, size_t ws_size,
                              hipStream_t stream) {
  const float* xin = (const float*)d_in[0];
  const float* nin = (const float*)d_in[1];
  float* out = (float*)d_out;

  double C[8];
  solve_coeffs(C);
  AugParams P;
  P.a = (float)C[0]; P.b = (float)C[1]; P.c = (float)C[2]; P.d = (float)C[3];
  P.e = (float)C[4]; P.f = (float)C[5]; P.g = (float)C[6]; P.h = (float)C[7];
  double t = 10.0 * M_PI / 180.0;
  P.cosT = (float)std::cos(t);
  P.sinT = (float)std::sin(t);

  const int total = NCH * HH * WW;                 // 19,267,584
  const size_t tbl_w_off = 0;                      // float4[224] = 3584 B
  const size_t tbl_i_off = 3584;                   // int4[224]   = 3584 B
  const size_t crop_off = 8192;
  const size_t need = crop_off + (size_t)NCH * CROP_STRIDE * sizeof(float);

  if (ws_size >= need) {
    float4* wt = (float4*)((char*)d_ws + tbl_w_off);
    int4*   it = (int4*)((char*)d_ws + tbl_i_off);
    float* crop = (float*)((char*)d_ws + crop_off);

    hipLaunchKernelGGL(table_kernel, dim3(1), dim3(256), 0, stream, wt, it);
    dim3 g1(NTIL * NTIL, NCH / GCH);               // (100, 48)
    hipLaunchKernelGGL(warp_tiled_kernel, g1, dim3(256), 0, stream, xin, nin, crop, P);
    dim3 g2(HH / STRIPROWS, NCH);                  // (8, 384)
    hipLaunchKernelGGL(resize_strips_kernel, g2, dim3(256), 0, stream, crop, wt, it, out);
  } else {
    hipLaunchKernelGGL(fused_fallback_kernel, dim3(2048), dim3(256), 0, stream,
                       xin, nin, out, P, total);
  }
}

// Round 5
// 126.673 us; speedup vs baseline: 3.8142x; 1.1160x over previous
//
#include <hip/hip_runtime.h>
#include <cmath>
#include <cstring>

#define HH 224
#define WW 224
#define CROP 160
#define CI 32
#define CJ 32
#define NCH 384                 // 128*3
#define CH_STRIDE (HH*WW)       // 50176
#define CROP_STRIDE (CROP*CROP) // 25600

// ---- pass-2 (pre-image gather) geometry ----
#define TILE2 32
#define NTIL2 5                 // 5x5 tiles of 32x32
#define GCH2 8                  // channels per block
#define BH2 64                  // phys LDS rows (row0 = logical -1 pad)
#define BHCAP 62                // max staged source rows
#define NG2 18                  // max ushort4 granules per row
#define BWSTR 77                // LDS row stride in floats (odd)
// LDS: 2 * 64 * 77 * 4B = 39424 B

// ---- direct-path (fallback) geometry (R4) ----
#define TILE 16
#define NTIL 10
#define GCH 8
#define BMAXH 33
#define BMAXW 35
#define LROWS 35
#define LSTR  37
#define LWORDS (LROWS*LSTR)

struct AugParams {
  float a, b, c, d, e, f, g, h;
  float cosT, sinT;
};

// ---------------------------------------------------------------------------
// Bicubic (Keys a=-0.5) axis weights, matching jax.image.resize.
// ---------------------------------------------------------------------------
__device__ __forceinline__ void axis_weights(int o, float w[4], int id[4]) {
  float s = (o + 0.5f) * (160.0f / 224.0f) - 0.5f;
  int base = (int)floorf(s) - 1;
  float sum = 0.0f;
#pragma unroll
  for (int t = 0; t < 4; ++t) {
    int ii = base + t;
    float dd = fabsf(s - (float)ii);
    float kw;
    if (dd < 1.0f)      kw = ((1.5f * dd - 2.5f) * dd) * dd + 1.0f;
    else if (dd < 2.0f) kw = ((-0.5f * dd + 2.5f) * dd - 4.0f) * dd + 2.0f;
    else                kw = 0.0f;
    if (ii < 0 || ii > CROP - 1) kw = 0.0f;
    w[t] = kw;
    sum += kw;
    id[t] = min(max(ii, 0), CROP - 1);
  }
  float inv = 1.0f / sum;
#pragma unroll
  for (int t = 0; t < 4; ++t) w[t] *= inv;
}

__global__ void table_kernel(float4* __restrict__ wt, int4* __restrict__ it) {
  int o = blockIdx.x * blockDim.x + threadIdx.x;
  if (o >= HH) return;
  float w[4]; int id[4];
  axis_weights(o, w, id);
  wt[o] = make_float4(w[0], w[1], w[2], w[3]);
  it[o] = make_int4(id[0], id[1], id[2], id[3]);
}

__device__ __forceinline__ float preproc(float v, float nv) {
  float p = (v + 0.45f * nv) * 1.1f;
  return fminf(fmaxf(p, 0.0f), 1.0f);
}

__device__ __forceinline__ float bf2f(unsigned short u) {
  return __uint_as_float(((unsigned int)u) << 16);
}

// ---------------------------------------------------------------------------
// Pass 1: streaming preproc, fp32 NCHW -> bf16 NCHW.
// ---------------------------------------------------------------------------
__global__ __launch_bounds__(256) void preproc_kernel(
    const float4* __restrict__ xin, const float4* __restrict__ nin,
    ushort4* __restrict__ pre, int n4) {
  int stride = gridDim.x * blockDim.x;
  for (int i = blockIdx.x * blockDim.x + threadIdx.x; i < n4; i += stride) {
    float4 x = xin[i];
    float4 n = nin[i];
    float p0 = preproc(x.x, n.x);
    float p1 = preproc(x.y, n.y);
    float p2 = preproc(x.z, n.z);
    float p3 = preproc(x.w, n.w);
    // bf16 round-to-nearest-even
    ushort4 o;
    unsigned int b0 = __float_as_uint(p0), b1 = __float_as_uint(p1);
    unsigned int b2 = __float_as_uint(p2), b3 = __float_as_uint(p3);
    o.x = (unsigned short)((b0 + 0x7fff + ((b0 >> 16) & 1)) >> 16);
    o.y = (unsigned short)((b1 + 0x7fff + ((b1 >> 16) & 1)) >> 16);
    o.z = (unsigned short)((b2 + 0x7fff + ((b2 >> 16) & 1)) >> 16);
    o.w = (unsigned short)((b3 + 0x7fff + ((b3 >> 16) & 1)) >> 16);
    pre[i] = o;
  }
}

// ---------------------------------------------------------------------------
// 16 combined taps (global coords, clamped) — fallback paths.
// ---------------------------------------------------------------------------
__device__ __forceinline__ void make_taps(int i, int j, const AugParams P,
                                          int txs[16], int tys[16], float wts[16]) {
  const float cx = (WW - 1) * 0.5f, cy = (HH - 1) * 0.5f;
  float xr = (float)(j + CJ), yr = (float)(i + CI);
  float dx = xr - cx, dy = yr - cy;
  float rx = cx + P.cosT * dx + P.sinT * dy;
  float ry = cy - P.sinT * dx + P.cosT * dy;
  float x0f = floorf(rx), y0f = floorf(ry);
  int x0 = (int)x0f, y0 = (int)y0f;
  float wx1 = rx - x0f, wy1 = ry - y0f;
  float rwx[2] = {1.0f - wx1, wx1};
  float rwy[2] = {1.0f - wy1, wy1};
  int k = 0;
#pragma unroll
  for (int ny = 0; ny < 2; ++ny) {
#pragma unroll
    for (int nx = 0; nx < 2; ++nx) {
      int yn = y0 + ny, xn = x0 + nx;
      bool vn = (xn >= 0 && xn <= WW - 1 && yn >= 0 && yn <= HH - 1);
      float wn = rwy[ny] * rwx[nx] * (vn ? 1.0f : 0.0f);
      float xo = (float)xn, yo = (float)yn;
      float inv = 1.0f / (P.g * xo + P.h * yo + 1.0f);
      float px = (P.a * xo + P.b * yo + P.c) * inv;
      float py = (P.d * xo + P.e * yo + P.f) * inv;
      float px0f = floorf(px), py0f = floorf(py);
      int px0 = (int)px0f, py0 = (int)py0f;
      float pwx1 = px - px0f, pwy1 = py - py0f;
      float pwx[2] = {1.0f - pwx1, pwx1};
      float pwy[2] = {1.0f - pwy1, pwy1};
#pragma unroll
      for (int ty = 0; ty < 2; ++ty) {
#pragma unroll
        for (int tx = 0; tx < 2; ++tx) {
          int yt = py0 + ty, xt = px0 + tx;
          bool vt = (xt >= 0 && xt <= WW - 1 && yt >= 0 && yt <= HH - 1);
          tys[k] = min(max(yt, 0), HH - 1);
          txs[k] = min(max(xt, 0), WW - 1);
          wts[k] = wn * pwy[ty] * pwx[tx] * (vt ? 1.0f : 0.0f);
          ++k;
        }
      }
    }
  }
}

// ---------------------------------------------------------------------------
// Patch origins (phys LDS offsets, BWSTR stride) + 16 weights for pixel (i,j).
// Logical: phys row = src_y - by0 + 1, phys col = src_x - bx0e + 4.
// Nonzero-weight taps always land in staged slots; weight-0 patches are
// clamped into the (zero/stale but finite) buffer.
// ---------------------------------------------------------------------------
__device__ __forceinline__ void make_patches2(int i, int j, const AugParams P,
                                              int by0, int bx0e,
                                              int pofs[4], float wts[16]) {
  const float cx = (WW - 1) * 0.5f, cy = (HH - 1) * 0.5f;
  float xr = (float)(j + CJ), yr = (float)(i + CI);
  float dx = xr - cx, dy = yr - cy;
  float rx = cx + P.cosT * dx + P.sinT * dy;
  float ry = cy - P.sinT * dx + P.cosT * dy;
  float x0f = floorf(rx), y0f = floorf(ry);
  int x0 = (int)x0f, y0 = (int)y0f;
  float wx1 = rx - x0f, wy1 = ry - y0f;
  float rwx[2] = {1.0f - wx1, wx1};
  float rwy[2] = {1.0f - wy1, wy1};
  int n = 0;
#pragma unroll
  for (int ny = 0; ny < 2; ++ny) {
#pragma unroll
    for (int nx = 0; nx < 2; ++nx) {
      int yn = y0 + ny, xn = x0 + nx;
      bool vn = (xn >= 0 && xn <= WW - 1 && yn >= 0 && yn <= HH - 1);
      float wn = rwy[ny] * rwx[nx] * (vn ? 1.0f : 0.0f);
      float xo = (float)xn, yo = (float)yn;
      float inv = 1.0f / (P.g * xo + P.h * yo + 1.0f);
      float px = (P.a * xo + P.b * yo + P.c) * inv;
      float py = (P.d * xo + P.e * yo + P.f) * inv;
      float px0f = floorf(px), py0f = floorf(py);
      int px0 = (int)px0f, py0 = (int)py0f;
      float pwx1 = px - px0f, pwy1 = py - py0f;
      float pwx[2] = {1.0f - pwx1, pwx1};
      float pwy[2] = {1.0f - pwy1, pwy1};
#pragma unroll
      for (int ty = 0; ty < 2; ++ty) {
#pragma unroll
        for (int tx = 0; tx < 2; ++tx) {
          int yt = py0 + ty, xt = px0 + tx;
          bool vt = (xt >= 0 && xt <= WW - 1 && yt >= 0 && yt <= HH - 1);
          wts[n * 4 + ty * 2 + tx] = wn * pwy[ty] * pwx[tx] * (vt ? 1.0f : 0.0f);
        }
      }
      int r0 = py0 - by0 + 1;
      int c0 = px0 - bx0e + 4;
      r0 = min(max(r0, 0), BH2 - 2);
      c0 = min(max(c0, 0), BWSTR - 2);
      pofs[n] = r0 * BWSTR + c0;
      ++n;
    }
  }
}

// ---------------------------------------------------------------------------
// Pass 2: block = 256 threads = one 32x32 crop tile x 8 channels.
// Stage bf16 pre bbox (ushort4 aligned loads, L3-resident) -> f32 LDS;
// double-buffered, async-split; taps held in registers across channels.
// ---------------------------------------------------------------------------
__global__ __launch_bounds__(256, 3) void warp_pre_kernel(
    const unsigned short* __restrict__ pre, float* __restrict__ crop,
    AugParams P) {
  __shared__ float s_img[2][BH2 * BWSTR];
  int tile = blockIdx.x;                 // 0..24
  int ch0  = blockIdx.y * GCH2;
  int i0 = (tile / NTIL2) * TILE2;
  int j0 = (tile % NTIL2) * TILE2;

  // ---- wave-uniform exact bbox via corner transforms ----
  const float cx = (WW - 1) * 0.5f, cy = (HH - 1) * 0.5f;
  float rxmin = 1e30f, rxmax = -1e30f, rymin = 1e30f, rymax = -1e30f;
#pragma unroll
  for (int c = 0; c < 4; ++c) {
    float xr = (float)(j0 + CJ + ((c & 1) ? TILE2 - 1 : 0));
    float yr = (float)(i0 + CI + ((c & 2) ? TILE2 - 1 : 0));
    float dx = xr - cx, dy = yr - cy;
    float rx = cx + P.cosT * dx + P.sinT * dy;
    float ry = cy - P.sinT * dx + P.cosT * dy;
    rxmin = fminf(rxmin, rx); rxmax = fmaxf(rxmax, rx);
    rymin = fminf(rymin, ry); rymax = fmaxf(rymax, ry);
  }
  float xnlo = floorf(rxmin), xnhi = floorf(rxmax) + 1.0f;
  float ynlo = floorf(rymin), ynhi = floorf(rymax) + 1.0f;
  float pxmin = 1e30f, pxmax = -1e30f, pymin = 1e30f, pymax = -1e30f;
#pragma unroll
  for (int c = 0; c < 4; ++c) {
    float xo = (c & 1) ? xnhi : xnlo;
    float yo = (c & 2) ? ynhi : ynlo;
    float inv = 1.0f / (P.g * xo + P.h * yo + 1.0f);
    float px = (P.a * xo + P.b * yo + P.c) * inv;
    float py = (P.d * xo + P.e * yo + P.f) * inv;
    pxmin = fminf(pxmin, px); pxmax = fmaxf(pxmax, px);
    pymin = fminf(pymin, py); pymax = fmaxf(pymax, py);
  }
  int bx0 = max(0, (int)floorf(pxmin));
  int bx1 = min(WW - 1, (int)floorf(pxmax) + 1);
  int by0 = max(0, (int)floorf(pymin));
  int by1 = min(HH - 1, (int)floorf(pymax) + 1);
  int bx0e = bx0 & ~3;                   // ushort4-aligned left edge
  int bh = by1 - by0 + 1;
  int gmax = (bx1 - bx0e + 4) >> 2;      // last granule index
  bool use_lds = (bh <= BHCAP) && (gmax <= NG2 - 1);

  int tid = threadIdx.x;

  if (use_lds) {
    // per-thread taps for 4 pixels, reused across all channels
    int pofs[4][4]; float wts[4][16];
#pragma unroll
    for (int k = 0; k < 4; ++k) {
      int p = tid + k * 256;
      make_patches2(i0 + (p >> 5), j0 + (p & 31), P, by0, bx0e, pofs[k], wts[k]);
    }

    // zero-init both buffers once (pads/unstaged slots must be finite)
    for (int s = tid; s < 2 * BH2 * BWSTR; s += 256)
      ((float*)s_img)[s] = 0.0f;
    __syncthreads();

    int nslots = bh * NG2;
    // prologue: stage channel ch0 into buffer 0
    {
      const unsigned short* pb = pre + (size_t)ch0 * CH_STRIDE;
#pragma unroll
      for (int q = 0; q < 5; ++q) {
        int s = tid + q * 256;
        if (s < nslots) {
          int r = s / NG2, g = s - r * NG2;
          int x = bx0e - 4 + g * 4;
          if (x >= 0 && g <= gmax) {
            ushort4 v = *(const ushort4*)(pb + (by0 + r) * WW + x);
            float* d = &s_img[0][(r + 1) * BWSTR + g * 4];
            d[0] = bf2f(v.x); d[1] = bf2f(v.y); d[2] = bf2f(v.z); d[3] = bf2f(v.w);
          }
        }
      }
      __syncthreads();
    }

    int buf = 0;
    for (int cc = 0; cc < GCH2; ++cc) {
      int ch = ch0 + cc;
      bool more = (cc < GCH2 - 1);
      // issue next channel's loads early
      ushort4 xv[5];
      if (more) {
        const unsigned short* pb = pre + (size_t)(ch + 1) * CH_STRIDE;
#pragma unroll
        for (int q = 0; q < 5; ++q) {
          int s = tid + q * 256;
          if (s < nslots) {
            int r = s / NG2, g = s - r * NG2;
            int x = bx0e - 4 + g * 4;
            if (x >= 0 && g <= gmax)
              xv[q] = *(const ushort4*)(pb + (by0 + r) * WW + x);
          }
        }
      }
      // gather current channel from LDS
      const float* sb = s_img[buf];
      float* cb = crop + (size_t)ch * CROP_STRIDE;
#pragma unroll
      for (int k = 0; k < 4; ++k) {
        int p = tid + k * 256;
        float acc = 0.0f;
#pragma unroll
        for (int n = 0; n < 4; ++n) {
          int o = pofs[k][n];
          float v00 = sb[o],         v01 = sb[o + 1];
          float v10 = sb[o + BWSTR], v11 = sb[o + BWSTR + 1];
          acc = fmaf(wts[k][n * 4 + 0], v00, acc);
          acc = fmaf(wts[k][n * 4 + 1], v01, acc);
          acc = fmaf(wts[k][n * 4 + 2], v10, acc);
          acc = fmaf(wts[k][n * 4 + 3], v11, acc);
        }
        cb[i0 * CROP + (p >> 5) * CROP + j0 + (p & 31)] = acc;
      }
      // write staged next channel into the other buffer
      if (more) {
        float* sw = s_img[buf ^ 1];
#pragma unroll
        for (int q = 0; q < 5; ++q) {
          int s = tid + q * 256;
          if (s < nslots) {
            int r = s / NG2, g = s - r * NG2;
            int x = bx0e - 4 + g * 4;
            if (x >= 0 && g <= gmax) {
              float* d = &sw[(r + 1) * BWSTR + g * 4];
              d[0] = bf2f(xv[q].x); d[1] = bf2f(xv[q].y);
              d[2] = bf2f(xv[q].z); d[3] = bf2f(xv[q].w);
            }
          }
        }
      }
      __syncthreads();
      buf ^= 1;
    }
  } else {
    // safety: direct gather from pre (L3-resident)
    for (int k = 0; k < 4; ++k) {
      int p = tid + k * 256;
      int i = i0 + (p >> 5), j = j0 + (p & 31);
      int txs[16], tys[16]; float w[16];
      make_taps(i, j, P, txs, tys, w);
      for (int cc = 0; cc < GCH2; ++cc) {
        int ch = ch0 + cc;
        const unsigned short* pb = pre + (size_t)ch * CH_STRIDE;
        float acc = 0.0f;
#pragma unroll
        for (int t = 0; t < 16; ++t)
          acc = fmaf(w[t], bf2f(pb[tys[t] * WW + txs[t]]), acc);
        crop[(size_t)ch * CROP_STRIDE + i * CROP + j] = acc;
      }
    }
  }
}

// ---------------------------------------------------------------------------
// Direct-path warp kernel (R4) — fallback when ws can't fit pre.
// ---------------------------------------------------------------------------
__device__ __forceinline__ void make_patches(int i, int j, const AugParams P,
                                             int by0, int bx0, int bh, int bw,
                                             int pofs[4], float wts[16]) {
  const float cx = (WW - 1) * 0.5f, cy = (HH - 1) * 0.5f;
  float xr = (float)(j + CJ), yr = (float)(i + CI);
  float dx = xr - cx, dy = yr - cy;
  float rx = cx + P.cosT * dx + P.sinT * dy;
  float ry = cy - P.sinT * dx + P.cosT * dy;
  float x0f = floorf(rx), y0f = floorf(ry);
  int x0 = (int)x0f, y0 = (int)y0f;
  float wx1 = rx - x0f, wy1 = ry - y0f;
  float rwx[2] = {1.0f - wx1, wx1};
  float rwy[2] = {1.0f - wy1, wy1};
  int n = 0;
#pragma unroll
  for (int ny = 0; ny < 2; ++ny) {
#pragma unroll
    for (int nx = 0; nx < 2; ++nx) {
      int yn = y0 + ny, xn = x0 + nx;
      bool vn = (xn >= 0 && xn <= WW - 1 && yn >= 0 && yn <= HH - 1);
      float wn = rwy[ny] * rwx[nx] * (vn ? 1.0f : 0.0f);
      float xo = (float)xn, yo = (float)yn;
      float inv = 1.0f / (P.g * xo + P.h * yo + 1.0f);
      float px = (P.a * xo + P.b * yo + P.c) * inv;
      float py = (P.d * xo + P.e * yo + P.f) * inv;
      float px0f = floorf(px), py0f = floorf(py);
      int px0 = (int)px0f, py0 = (int)py0f;
      float pwx1 = px - px0f, pwy1 = py - py0f;
      float pwx[2] = {1.0f - pwx1, pwx1};
      float pwy[2] = {1.0f - pwy1, pwy1};
#pragma unroll
      for (int ty = 0; ty < 2; ++ty) {
#pragma unroll
        for (int tx = 0; tx < 2; ++tx) {
          int yt = py0 + ty, xt = px0 + tx;
          bool vt = (xt >= 0 && xt <= WW - 1 && yt >= 0 && yt <= HH - 1);
          wts[n * 4 + ty * 2 + tx] = wn * pwy[ty] * pwx[tx] * (vt ? 1.0f : 0.0f);
        }
      }
      int ly = py0 - by0;
      int lx = px0 - bx0;
      if (ly < -1 || ly > bh - 1) ly = 0;
      if (lx < -1 || lx > bw - 1) lx = 0;
      pofs[n] = (ly + 1) * LSTR + (lx + 1);
      ++n;
    }
  }
}

__global__ __launch_bounds__(256) void warp_direct_kernel(
    const float* __restrict__ xin, const float* __restrict__ nin,
    float* __restrict__ crop, AugParams P) {
  __shared__ float s_img[2][LWORDS];
  int tile = blockIdx.x;
  int ch0  = blockIdx.y * GCH;
  int i0 = (tile / NTIL) * TILE;
  int j0 = (tile % NTIL) * TILE;

  const float cx = (WW - 1) * 0.5f, cy = (HH - 1) * 0.5f;
  float rxmin = 1e30f, rxmax = -1e30f, rymin = 1e30f, rymax = -1e30f;
#pragma unroll
  for (int c = 0; c < 4; ++c) {
    float xr = (float)(j0 + CJ + ((c & 1) ? TILE - 1 : 0));
    float yr = (float)(i0 + CI + ((c & 2) ? TILE - 1 : 0));
    float dx = xr - cx, dy = yr - cy;
    float rx = cx + P.cosT * dx + P.sinT * dy;
    float ry = cy - P.sinT * dx + P.cosT * dy;
    rxmin = fminf(rxmin, rx); rxmax = fmaxf(rxmax, rx);
    rymin = fminf(rymin, ry); rymax = fmaxf(rymax, ry);
  }
  float xnlo = floorf(rxmin), xnhi = floorf(rxmax) + 1.0f;
  float ynlo = floorf(rymin), ynhi = floorf(rymax) + 1.0f;
  float pxmin = 1e30f, pxmax = -1e30f, pymin = 1e30f, pymax = -1e30f;
#pragma unroll
  for (int c = 0; c < 4; ++c) {
    float xo = (c & 1) ? xnhi : xnlo;
    float yo = (c & 2) ? ynhi : ynlo;
    float inv = 1.0f / (P.g * xo + P.h * yo + 1.0f);
    float px = (P.a * xo + P.b * yo + P.c) * inv;
    float py = (P.d * xo + P.e * yo + P.f) * inv;
    pxmin = fminf(pxmin, px); pxmax = fmaxf(pxmax, px);
    pymin = fminf(pymin, py); pymax = fmaxf(pymax, py);
  }
  int bx0 = max(0, (int)floorf(pxmin));
  int bx1 = min(WW - 1, (int)floorf(pxmax) + 1);
  int by0 = max(0, (int)floorf(pymin));
  int by1 = min(HH - 1, (int)floorf(pymax) + 1);
  int bw = bx1 - bx0 + 1;
  int bh = by1 - by0 + 1;
  bool use_lds = (bw <= BMAXW && bh <= BMAXH);

  int tid = threadIdx.x;
  int i = i0 + (tid >> 4);
  int j = j0 + (tid & 15);
  int opix = i * CROP + j;

  if (use_lds) {
    int pofs[4]; float wts[16];
    make_patches(i, j, P, by0, bx0, bh, bw, pofs, wts);
    for (int s = tid; s < 2 * LWORDS; s += 256)
      ((float*)s_img)[s] = 0.0f;
    __syncthreads();
    {
      const float* xb = xin + (size_t)ch0 * CH_STRIDE;
      const float* nb = nin + (size_t)ch0 * CH_STRIDE;
      int r = tid >> 5, c = tid & 31;
#pragma unroll
      for (int rr = 0; rr < 5; ++rr) {
        int rcur = r + rr * 8;
        if (rcur < bh && c < bw) {
          int g = (by0 + rcur) * WW + bx0 + c;
          s_img[0][(rcur + 1) * LSTR + (c + 1)] = preproc(xb[g], nb[g]);
        }
      }
      if (bw > 32) {
        int r2 = tid >> 2, c2 = 32 + (tid & 3);
        if (r2 < bh && c2 < bw) {
          int g = (by0 + r2) * WW + bx0 + c2;
          s_img[0][(r2 + 1) * LSTR + (c2 + 1)] = preproc(xb[g], nb[g]);
        }
      }
      __syncthreads();
    }
    int buf = 0;
    int r = tid >> 5, c = tid & 31;
    int r2 = tid >> 2, c2 = 32 + (tid & 3);
    for (int cc = 0; cc < GCH; ++cc) {
      int ch = ch0 + cc;
      bool more = (cc < GCH - 1);
      float xv[5], nv[5], xe = 0.0f, ne = 0.0f;
      if (more) {
        const float* xb = xin + (size_t)(ch + 1) * CH_STRIDE;
        const float* nb = nin + (size_t)(ch + 1) * CH_STRIDE;
#pragma unroll
        for (int rr = 0; rr < 5; ++rr) {
          int rcur = r + rr * 8;
          if (rcur < bh && c < bw) {
            int g = (by0 + rcur) * WW + bx0 + c;
            xv[rr] = xb[g]; nv[rr] = nb[g];
          }
        }
        if (bw > 32 && r2 < bh && c2 < bw) {
          int g = (by0 + r2) * WW + bx0 + c2;
          xe = xb[g]; ne = nb[g];
        }
      }
      const float* sb = s_img[buf];
      float acc = 0.0f;
#pragma unroll
      for (int n = 0; n < 4; ++n) {
        int p = pofs[n];
        acc = fmaf(wts[n * 4 + 0], sb[p], acc);
        acc = fmaf(wts[n * 4 + 1], sb[p + 1], acc);
        acc = fmaf(wts[n * 4 + 2], sb[p + LSTR], acc);
        acc = fmaf(wts[n * 4 + 3], sb[p + LSTR + 1], acc);
      }
      crop[(size_t)ch * CROP_STRIDE + opix] = acc;
      if (more) {
        float* sw = s_img[buf ^ 1];
#pragma unroll
        for (int rr = 0; rr < 5; ++rr) {
          int rcur = r + rr * 8;
          if (rcur < bh && c < bw)
            sw[(rcur + 1) * LSTR + (c + 1)] = preproc(xv[rr], nv[rr]);
        }
        if (bw > 32 && r2 < bh && c2 < bw)
          sw[(r2 + 1) * LSTR + (c2 + 1)] = preproc(xe, ne);
      }
      __syncthreads();
      buf ^= 1;
    }
  } else {
    int txs[16], tys[16]; float wts[16];
    make_taps(i, j, P, txs, tys, wts);
    for (int cc = 0; cc < GCH; ++cc) {
      int ch = ch0 + cc;
      const float* xb = xin + (size_t)ch * CH_STRIDE;
      const float* nb = nin + (size_t)ch * CH_STRIDE;
      float acc = 0.0f;
#pragma unroll
      for (int t = 0; t < 16; ++t) {
        int g = tys[t] * WW + txs[t];
        acc = fmaf(wts[t], preproc(xb[g], nb[g]), acc);
      }
      crop[(size_t)ch * CROP_STRIDE + opix] = acc;
    }
  }
}

// ---------------------------------------------------------------------------
// Kernel: separable bicubic 160->224, strip per (channel, 28 rows).
// ---------------------------------------------------------------------------
#define STRIPROWS 28
#define HROWS 25
__global__ __launch_bounds__(256) void resize_strips_kernel(
    const float* __restrict__ crop, const float4* __restrict__ wt,
    const int4* __restrict__ it, float* __restrict__ out) {
  __shared__ float hbuf[HROWS * WW];
  int s = blockIdx.x;
  int ch = blockIdx.y;
  int r0 = max(0, s * 20 - 2);
  const float* cb = crop + (size_t)ch * CROP_STRIDE;
  int tid = threadIdx.x;

  for (int e = tid; e < HROWS * WW; e += 256) {
    int r = e / WW;
    int xo = e - r * WW;
    int cr = min(r0 + r, CROP - 1);
    float4 wx = wt[xo]; int4 ix = it[xo];
    const float* row = cb + cr * CROP;
    hbuf[e] = wx.x * row[ix.x] + wx.y * row[ix.y] +
              wx.z * row[ix.z] + wx.w * row[ix.w];
  }
  __syncthreads();
  for (int e = tid; e < STRIPROWS * WW; e += 256) {
    int yl = e / WW;
    int xo = e - yl * WW;
    int yo = s * STRIPROWS + yl;
    float4 wy = wt[yo]; int4 iy = it[yo];
    float o = wy.x * hbuf[(iy.x - r0) * WW + xo] +
              wy.y * hbuf[(iy.y - r0) * WW + xo] +
              wy.z * hbuf[(iy.z - r0) * WW + xo] +
              wy.w * hbuf[(iy.w - r0) * WW + xo];
    out[((size_t)ch * HH + yo) * WW + xo] = o;
  }
}

// ---------------------------------------------------------------------------
// Fully fused fallback (tiny ws).
// ---------------------------------------------------------------------------
__device__ float crop_val(const float* __restrict__ xb, const float* __restrict__ nb,
                          int i, int j, AugParams P) {
  int txs[16], tys[16]; float wts[16];
  make_taps(i, j, P, txs, tys, wts);
  float acc = 0.0f;
#pragma unroll
  for (int t = 0; t < 16; ++t)
    acc = fmaf(wts[t], preproc(xb[tys[t] * WW + txs[t]], nb[tys[t] * WW + txs[t]]), acc);
  return acc;
}

__global__ __launch_bounds__(256) void fused_fallback_kernel(
    const float* __restrict__ xin, const float* __restrict__ nin,
    float* __restrict__ out, AugParams P, int total) {
  int stride = gridDim.x * blockDim.x;
  for (int idx = blockIdx.x * blockDim.x + threadIdx.x; idx < total; idx += stride) {
    int xo = idx % WW;
    int t2 = idx / WW;
    int yo = t2 % HH;
    int ch = t2 / HH;
    float wxa[4]; int ixa[4]; axis_weights(xo, wxa, ixa);
    float wya[4]; int iya[4]; axis_weights(yo, wya, iya);
    const float* xb = xin + (size_t)ch * CH_STRIDE;
    const float* nb = nin + (size_t)ch * CH_STRIDE;
    float acc = 0.0f;
#pragma unroll
    for (int ty = 0; ty < 4; ++ty)
#pragma unroll
      for (int tx = 0; tx < 4; ++tx)
        acc += wya[ty] * wxa[tx] * crop_val(xb, nb, iya[ty], ixa[tx], P);
    out[idx] = acc;
  }
}

// ---------------------------------------------------------------------------
// Host: solve 8x8 perspective system.
// ---------------------------------------------------------------------------
static void solve_coeffs(double C[8]) {
  const double sp[4][2] = {{0, 0}, {223, 0}, {223, 223}, {0, 223}};
  const double ep[4][2] = {{30, 20}, {200, 25}, {210, 200}, {15, 190}};
  double A[8][9];
  for (int k = 0; k < 4; ++k) {
    double xi = sp[k][0], yi = sp[k][1], xo = ep[k][0], yo = ep[k][1];
    double r0[9] = {xo, yo, 1, 0, 0, 0, -xo * xi, -yo * xi, xi};
    double r1[9] = {0, 0, 0, xo, yo, 1, -xo * yi, -yo * yi, yi};
    std::memcpy(A[2 * k], r0, sizeof r0);
    std::memcpy(A[2 * k + 1], r1, sizeof r1);
  }
  for (int col = 0; col < 8; ++col) {
    int piv = col;
    for (int r = col + 1; r < 8; ++r)
      if (std::fabs(A[r][col]) > std::fabs(A[piv][col])) piv = r;
    if (piv != col)
      for (int cc = 0; cc < 9; ++cc) { double t = A[col][cc]; A[col][cc] = A[piv][cc]; A[piv][cc] = t; }
    double p = A[col][col];
    for (int r = 0; r < 8; ++r) {
      if (r == col) continue;
      double fmul = A[r][col] / p;
      for (int cc = col; cc < 9; ++cc) A[r][cc] -= fmul * A[col][cc];
    }
  }
  for (int r = 0; r < 8; ++r) C[r] = A[r][8] / A[r][r];
}

extern "C" void kernel_launch(void* const* d_in, const int* in_sizes, int n_in,
                              void* d_out, int out_size, void* d_ws, size_t ws_size,
                              hipStream_t stream) {
  const float* xin = (const float*)d_in[0];
  const float* nin = (const float*)d_in[1];
  float* out = (float*)d_out;

  double C[8];
  solve_coeffs(C);
  AugParams P;
  P.a = (float)C[0]; P.b = (float)C[1]; P.c = (float)C[2]; P.d = (float)C[3];
  P.e = (float)C[4]; P.f = (float)C[5]; P.g = (float)C[6]; P.h = (float)C[7];
  double t = 10.0 * M_PI / 180.0;
  P.cosT = (float)std::cos(t);
  P.sinT = (float)std::sin(t);

  const int total = NCH * HH * WW;                 // 19,267,584
  const size_t PRE_BYTES = (size_t)NCH * CH_STRIDE * 2;      // 38,535,168
  const size_t CROP_BYTES = (size_t)NCH * CROP_STRIDE * 4;   // 39,321,600

  // full layout: [pre][256 slack][wt][it][crop]
  const size_t TBLW_OFF = PRE_BYTES + 256;
  const size_t TBLI_OFF = TBLW_OFF + 3584;
  const size_t CROPF_OFF = TBLI_OFF + 3584;
  const size_t need_full = CROPF_OFF + CROP_BYTES;
  // medium layout: [wt][it][crop]
  const size_t need_med = 8192 + CROP_BYTES;

  if (ws_size >= need_full) {
    unsigned short* pre = (unsigned short*)d_ws;
    float4* wt = (float4*)((char*)d_ws + TBLW_OFF);
    int4*   it = (int4*)((char*)d_ws + TBLI_OFF);
    float* crop = (float*)((char*)d_ws + CROPF_OFF);

    hipLaunchKernelGGL(table_kernel, dim3(1), dim3(256), 0, stream, wt, it);
    hipLaunchKernelGGL(preproc_kernel, dim3(2048), dim3(256), 0, stream,
                       (const float4*)xin, (const float4*)nin,
                       (ushort4*)pre, total / 4);
    dim3 g1(NTIL2 * NTIL2, NCH / GCH2);            // (25, 48)
    hipLaunchKernelGGL(warp_pre_kernel, g1, dim3(256), 0, stream, pre, crop, P);
    dim3 g2(HH / STRIPROWS, NCH);                  // (8, 384)
    hipLaunchKernelGGL(resize_strips_kernel, g2, dim3(256), 0, stream, crop, wt, it, out);
  } else if (ws_size >= need_med) {
    float4* wt = (float4*)d_ws;
    int4*   it = (int4*)((char*)d_ws + 3584);
    float* crop = (float*)((char*)d_ws + 8192);

    hipLaunchKernelGGL(table_kernel, dim3(1), dim3(256), 0, stream, wt, it);
    dim3 g1(NTIL * NTIL, NCH / GCH);               // (100, 48)
    hipLaunchKernelGGL(warp_direct_kernel, g1, dim3(256), 0, stream, xin, nin, crop, P);
    dim3 g2(HH / STRIPROWS, NCH);
    hipLaunchKernelGGL(resize_strips_kernel, g2, dim3(256), 0, stream, crop, wt, it, out);
  } else {
    hipLaunchKernelGGL(fused_fallback_kernel, dim3(2048), dim3(256), 0, stream,
                       xin, nin, out, P, total);
  }
}

// Round 6
// 120.975 us; speedup vs baseline: 3.9938x; 1.0471x over previous
//
#include <hip/hip_runtime.h>
#include <cmath>
#include <cstring>

#define HH 224
#define WW 224
#define CROP 160
#define CI 32
#define CJ 32
#define NCH 384                 // 128*3
#define CH_STRIDE (HH*WW)       // 50176
#define CROP_STRIDE (CROP*CROP) // 25600

// ---- pass-2 (pre-image gather) geometry ----
#define TILE2 32
#define NTIL2 5                 // 5x5 tiles of 32x32
#define GCH2 8                  // channels per block
#define BH2 64                  // phys LDS rows (row0 = logical -1 pad)
#define BHCAP 62                // max staged source rows
#define NG2 18                  // max ushort4 granules per row
#define BWSTR 80                // LDS row stride in floats (16B-aligned granules)
// LDS: 2 * 64 * 80 * 4B = 40960 B

// ---- direct-path (fallback) geometry (R4) ----
#define TILE 16
#define NTIL 10
#define GCH 8
#define BMAXH 33
#define BMAXW 35
#define LROWS 35
#define LSTR  37
#define LWORDS (LROWS*LSTR)

struct AugParams {
  float a, b, c, d, e, f, g, h;
  float cosT, sinT;
};

// ---------------------------------------------------------------------------
// Bicubic (Keys a=-0.5) axis weights, matching jax.image.resize.
// ---------------------------------------------------------------------------
__device__ __forceinline__ void axis_weights(int o, float w[4], int id[4]) {
  float s = (o + 0.5f) * (160.0f / 224.0f) - 0.5f;
  int base = (int)floorf(s) - 1;
  float sum = 0.0f;
#pragma unroll
  for (int t = 0; t < 4; ++t) {
    int ii = base + t;
    float dd = fabsf(s - (float)ii);
    float kw;
    if (dd < 1.0f)      kw = ((1.5f * dd - 2.5f) * dd) * dd + 1.0f;
    else if (dd < 2.0f) kw = ((-0.5f * dd + 2.5f) * dd - 4.0f) * dd + 2.0f;
    else                kw = 0.0f;
    if (ii < 0 || ii > CROP - 1) kw = 0.0f;
    w[t] = kw;
    sum += kw;
    id[t] = min(max(ii, 0), CROP - 1);
  }
  float inv = 1.0f / sum;
#pragma unroll
  for (int t = 0; t < 4; ++t) w[t] *= inv;
}

__global__ void table_kernel(float4* __restrict__ wt, int4* __restrict__ it) {
  int o = blockIdx.x * blockDim.x + threadIdx.x;
  if (o >= HH) return;
  float w[4]; int id[4];
  axis_weights(o, w, id);
  wt[o] = make_float4(w[0], w[1], w[2], w[3]);
  it[o] = make_int4(id[0], id[1], id[2], id[3]);
}

__device__ __forceinline__ float preproc(float v, float nv) {
  float p = (v + 0.45f * nv) * 1.1f;
  return fminf(fmaxf(p, 0.0f), 1.0f);
}

__device__ __forceinline__ float bf2f(unsigned short u) {
  return __uint_as_float(((unsigned int)u) << 16);
}

__device__ __forceinline__ unsigned short f2bf(float f) {
  unsigned int b = __float_as_uint(f);
  return (unsigned short)((b + 0x7fff + ((b >> 16) & 1)) >> 16);
}

// ---------------------------------------------------------------------------
// Pass 1: streaming preproc, fp32 NCHW -> bf16 NCHW.
// 16 floats per thread (4 consecutive float4 pairs), fully unrolled:
// 8 independent 16B loads in flight -> latency-robust.
// Exact cover: total/16 threads.
// ---------------------------------------------------------------------------
__global__ __launch_bounds__(256) void preproc_kernel(
    const float4* __restrict__ xin, const float4* __restrict__ nin,
    ushort4* __restrict__ pre) {
  int t = blockIdx.x * 256 + threadIdx.x;
  int b = t * 4;
  float4 x0 = xin[b + 0], x1 = xin[b + 1], x2 = xin[b + 2], x3 = xin[b + 3];
  float4 n0 = nin[b + 0], n1 = nin[b + 1], n2 = nin[b + 2], n3 = nin[b + 3];
  ushort4 o0, o1, o2, o3;
  o0.x = f2bf(preproc(x0.x, n0.x)); o0.y = f2bf(preproc(x0.y, n0.y));
  o0.z = f2bf(preproc(x0.z, n0.z)); o0.w = f2bf(preproc(x0.w, n0.w));
  o1.x = f2bf(preproc(x1.x, n1.x)); o1.y = f2bf(preproc(x1.y, n1.y));
  o1.z = f2bf(preproc(x1.z, n1.z)); o1.w = f2bf(preproc(x1.w, n1.w));
  o2.x = f2bf(preproc(x2.x, n2.x)); o2.y = f2bf(preproc(x2.y, n2.y));
  o2.z = f2bf(preproc(x2.z, n2.z)); o2.w = f2bf(preproc(x2.w, n2.w));
  o3.x = f2bf(preproc(x3.x, n3.x)); o3.y = f2bf(preproc(x3.y, n3.y));
  o3.z = f2bf(preproc(x3.z, n3.z)); o3.w = f2bf(preproc(x3.w, n3.w));
  pre[b + 0] = o0; pre[b + 1] = o1; pre[b + 2] = o2; pre[b + 3] = o3;
}

// ---------------------------------------------------------------------------
// 16 combined taps (global coords, clamped) — fallback paths.
// ---------------------------------------------------------------------------
__device__ __forceinline__ void make_taps(int i, int j, const AugParams P,
                                          int txs[16], int tys[16], float wts[16]) {
  const float cx = (WW - 1) * 0.5f, cy = (HH - 1) * 0.5f;
  float xr = (float)(j + CJ), yr = (float)(i + CI);
  float dx = xr - cx, dy = yr - cy;
  float rx = cx + P.cosT * dx + P.sinT * dy;
  float ry = cy - P.sinT * dx + P.cosT * dy;
  float x0f = floorf(rx), y0f = floorf(ry);
  int x0 = (int)x0f, y0 = (int)y0f;
  float wx1 = rx - x0f, wy1 = ry - y0f;
  float rwx[2] = {1.0f - wx1, wx1};
  float rwy[2] = {1.0f - wy1, wy1};
  int k = 0;
#pragma unroll
  for (int ny = 0; ny < 2; ++ny) {
#pragma unroll
    for (int nx = 0; nx < 2; ++nx) {
      int yn = y0 + ny, xn = x0 + nx;
      bool vn = (xn >= 0 && xn <= WW - 1 && yn >= 0 && yn <= HH - 1);
      float wn = rwy[ny] * rwx[nx] * (vn ? 1.0f : 0.0f);
      float xo = (float)xn, yo = (float)yn;
      float inv = 1.0f / (P.g * xo + P.h * yo + 1.0f);
      float px = (P.a * xo + P.b * yo + P.c) * inv;
      float py = (P.d * xo + P.e * yo + P.f) * inv;
      float px0f = floorf(px), py0f = floorf(py);
      int px0 = (int)px0f, py0 = (int)py0f;
      float pwx1 = px - px0f, pwy1 = py - py0f;
      float pwx[2] = {1.0f - pwx1, pwx1};
      float pwy[2] = {1.0f - pwy1, pwy1};
#pragma unroll
      for (int ty = 0; ty < 2; ++ty) {
#pragma unroll
        for (int tx = 0; tx < 2; ++tx) {
          int yt = py0 + ty, xt = px0 + tx;
          bool vt = (xt >= 0 && xt <= WW - 1 && yt >= 0 && yt <= HH - 1);
          tys[k] = min(max(yt, 0), HH - 1);
          txs[k] = min(max(xt, 0), WW - 1);
          wts[k] = wn * pwy[ty] * pwx[tx] * (vt ? 1.0f : 0.0f);
          ++k;
        }
      }
    }
  }
}

// ---------------------------------------------------------------------------
// Patch origins (phys LDS offsets, BWSTR stride) + 16 weights for pixel (i,j).
// ---------------------------------------------------------------------------
__device__ __forceinline__ void make_patches2(int i, int j, const AugParams P,
                                              int by0, int bx0e,
                                              int pofs[4], float wts[16]) {
  const float cx = (WW - 1) * 0.5f, cy = (HH - 1) * 0.5f;
  float xr = (float)(j + CJ), yr = (float)(i + CI);
  float dx = xr - cx, dy = yr - cy;
  float rx = cx + P.cosT * dx + P.sinT * dy;
  float ry = cy - P.sinT * dx + P.cosT * dy;
  float x0f = floorf(rx), y0f = floorf(ry);
  int x0 = (int)x0f, y0 = (int)y0f;
  float wx1 = rx - x0f, wy1 = ry - y0f;
  float rwx[2] = {1.0f - wx1, wx1};
  float rwy[2] = {1.0f - wy1, wy1};
  int n = 0;
#pragma unroll
  for (int ny = 0; ny < 2; ++ny) {
#pragma unroll
    for (int nx = 0; nx < 2; ++nx) {
      int yn = y0 + ny, xn = x0 + nx;
      bool vn = (xn >= 0 && xn <= WW - 1 && yn >= 0 && yn <= HH - 1);
      float wn = rwy[ny] * rwx[nx] * (vn ? 1.0f : 0.0f);
      float xo = (float)xn, yo = (float)yn;
      float inv = 1.0f / (P.g * xo + P.h * yo + 1.0f);
      float px = (P.a * xo + P.b * yo + P.c) * inv;
      float py = (P.d * xo + P.e * yo + P.f) * inv;
      float px0f = floorf(px), py0f = floorf(py);
      int px0 = (int)px0f, py0 = (int)py0f;
      float pwx1 = px - px0f, pwy1 = py - py0f;
      float pwx[2] = {1.0f - pwx1, pwx1};
      float pwy[2] = {1.0f - pwy1, pwy1};
#pragma unroll
      for (int ty = 0; ty < 2; ++ty) {
#pragma unroll
        for (int tx = 0; tx < 2; ++tx) {
          int yt = py0 + ty, xt = px0 + tx;
          bool vt = (xt >= 0 && xt <= WW - 1 && yt >= 0 && yt <= HH - 1);
          wts[n * 4 + ty * 2 + tx] = wn * pwy[ty] * pwx[tx] * (vt ? 1.0f : 0.0f);
        }
      }
      int r0 = py0 - by0 + 1;
      int c0 = px0 - bx0e + 4;
      r0 = min(max(r0, 0), BH2 - 2);
      c0 = min(max(c0, 0), BWSTR - 2);
      pofs[n] = r0 * BWSTR + c0;
      ++n;
    }
  }
}

// ---------------------------------------------------------------------------
// Pass 2: block = 256 threads = one 32x32 crop tile x 8 channels.
// bf16 pre bbox staged via ushort4 loads -> float4 (ds_write_b128) into
// 16B-aligned LDS granules; double-buffered; taps in registers.
// ---------------------------------------------------------------------------
__global__ __launch_bounds__(256, 3) void warp_pre_kernel(
    const unsigned short* __restrict__ pre, float* __restrict__ crop,
    AugParams P) {
  __shared__ float s_img[2][BH2 * BWSTR];
  int tile = blockIdx.x;                 // 0..24
  int ch0  = blockIdx.y * GCH2;
  int i0 = (tile / NTIL2) * TILE2;
  int j0 = (tile % NTIL2) * TILE2;

  // ---- wave-uniform exact bbox via corner transforms ----
  const float cx = (WW - 1) * 0.5f, cy = (HH - 1) * 0.5f;
  float rxmin = 1e30f, rxmax = -1e30f, rymin = 1e30f, rymax = -1e30f;
#pragma unroll
  for (int c = 0; c < 4; ++c) {
    float xr = (float)(j0 + CJ + ((c & 1) ? TILE2 - 1 : 0));
    float yr = (float)(i0 + CI + ((c & 2) ? TILE2 - 1 : 0));
    float dx = xr - cx, dy = yr - cy;
    float rx = cx + P.cosT * dx + P.sinT * dy;
    float ry = cy - P.sinT * dx + P.cosT * dy;
    rxmin = fminf(rxmin, rx); rxmax = fmaxf(rxmax, rx);
    rymin = fminf(rymin, ry); rymax = fmaxf(rymax, ry);
  }
  float xnlo = floorf(rxmin), xnhi = floorf(rxmax) + 1.0f;
  float ynlo = floorf(rymin), ynhi = floorf(rymax) + 1.0f;
  float pxmin = 1e30f, pxmax = -1e30f, pymin = 1e30f, pymax = -1e30f;
#pragma unroll
  for (int c = 0; c < 4; ++c) {
    float xo = (c & 1) ? xnhi : xnlo;
    float yo = (c & 2) ? ynhi : ynlo;
    float inv = 1.0f / (P.g * xo + P.h * yo + 1.0f);
    float px = (P.a * xo + P.b * yo + P.c) * inv;
    float py = (P.d * xo + P.e * yo + P.f) * inv;
    pxmin = fminf(pxmin, px); pxmax = fmaxf(pxmax, px);
    pymin = fminf(pymin, py); pymax = fmaxf(pymax, py);
  }
  int bx0 = max(0, (int)floorf(pxmin));
  int bx1 = min(WW - 1, (int)floorf(pxmax) + 1);
  int by0 = max(0, (int)floorf(pymin));
  int by1 = min(HH - 1, (int)floorf(pymax) + 1);
  int bx0e = bx0 & ~3;                   // ushort4-aligned left edge
  int bh = by1 - by0 + 1;
  int gmax = (bx1 - bx0e + 4) >> 2;      // last granule index
  bool use_lds = (bh <= BHCAP) && (gmax <= NG2 - 1);

  int tid = threadIdx.x;

  if (use_lds) {
    // per-thread taps for 4 pixels, reused across all channels
    int pofs[4][4]; float wts[4][16];
#pragma unroll
    for (int k = 0; k < 4; ++k) {
      int p = tid + k * 256;
      make_patches2(i0 + (p >> 5), j0 + (p & 31), P, by0, bx0e, pofs[k], wts[k]);
    }

    // zero-init both buffers once (pads/unstaged slots must be finite)
    for (int s = tid; s < 2 * BH2 * BWSTR; s += 256)
      ((float*)s_img)[s] = 0.0f;
    __syncthreads();

    int nslots = bh * NG2;
    // prologue: stage channel ch0 into buffer 0
    {
      const unsigned short* pb = pre + (size_t)ch0 * CH_STRIDE;
#pragma unroll
      for (int q = 0; q < 5; ++q) {
        int s = tid + q * 256;
        if (s < nslots) {
          int r = s / NG2, g = s - r * NG2;
          int x = bx0e - 4 + g * 4;
          if (x >= 0 && g <= gmax) {
            ushort4 v = *(const ushort4*)(pb + (by0 + r) * WW + x);
            *(float4*)&s_img[0][(r + 1) * BWSTR + g * 4] =
                make_float4(bf2f(v.x), bf2f(v.y), bf2f(v.z), bf2f(v.w));
          }
        }
      }
      __syncthreads();
    }

    int buf = 0;
    for (int cc = 0; cc < GCH2; ++cc) {
      int ch = ch0 + cc;
      bool more = (cc < GCH2 - 1);
      // issue next channel's loads early
      ushort4 xv[5];
      if (more) {
        const unsigned short* pb = pre + (size_t)(ch + 1) * CH_STRIDE;
#pragma unroll
        for (int q = 0; q < 5; ++q) {
          int s = tid + q * 256;
          if (s < nslots) {
            int r = s / NG2, g = s - r * NG2;
            int x = bx0e - 4 + g * 4;
            if (x >= 0 && g <= gmax)
              xv[q] = *(const ushort4*)(pb + (by0 + r) * WW + x);
          }
        }
      }
      // gather current channel from LDS
      const float* sb = s_img[buf];
      float* cb = crop + (size_t)ch * CROP_STRIDE;
#pragma unroll
      for (int k = 0; k < 4; ++k) {
        int p = tid + k * 256;
        float acc = 0.0f;
#pragma unroll
        for (int n = 0; n < 4; ++n) {
          int o = pofs[k][n];
          float v00 = sb[o],         v01 = sb[o + 1];
          float v10 = sb[o + BWSTR], v11 = sb[o + BWSTR + 1];
          acc = fmaf(wts[k][n * 4 + 0], v00, acc);
          acc = fmaf(wts[k][n * 4 + 1], v01, acc);
          acc = fmaf(wts[k][n * 4 + 2], v10, acc);
          acc = fmaf(wts[k][n * 4 + 3], v11, acc);
        }
        cb[i0 * CROP + (p >> 5) * CROP + j0 + (p & 31)] = acc;
      }
      // write staged next channel into the other buffer
      if (more) {
        float* sw = s_img[buf ^ 1];
#pragma unroll
        for (int q = 0; q < 5; ++q) {
          int s = tid + q * 256;
          if (s < nslots) {
            int r = s / NG2, g = s - r * NG2;
            int x = bx0e - 4 + g * 4;
            if (x >= 0 && g <= gmax) {
              *(float4*)&sw[(r + 1) * BWSTR + g * 4] =
                  make_float4(bf2f(xv[q].x), bf2f(xv[q].y),
                              bf2f(xv[q].z), bf2f(xv[q].w));
            }
          }
        }
      }
      __syncthreads();
      buf ^= 1;
    }
  } else {
    // safety: direct gather from pre (L3-resident)
    for (int k = 0; k < 4; ++k) {
      int p = tid + k * 256;
      int i = i0 + (p >> 5), j = j0 + (p & 31);
      int txs[16], tys[16]; float w[16];
      make_taps(i, j, P, txs, tys, w);
      for (int cc = 0; cc < GCH2; ++cc) {
        int ch = ch0 + cc;
        const unsigned short* pb = pre + (size_t)ch * CH_STRIDE;
        float acc = 0.0f;
#pragma unroll
        for (int t = 0; t < 16; ++t)
          acc = fmaf(w[t], bf2f(pb[tys[t] * WW + txs[t]]), acc);
        crop[(size_t)ch * CROP_STRIDE + i * CROP + j] = acc;
      }
    }
  }
}

// ---------------------------------------------------------------------------
// Direct-path warp kernel (fallback when ws can't fit pre).
// ---------------------------------------------------------------------------
__device__ __forceinline__ void make_patches(int i, int j, const AugParams P,
                                             int by0, int bx0, int bh, int bw,
                                             int pofs[4], float wts[16]) {
  const float cx = (WW - 1) * 0.5f, cy = (HH - 1) * 0.5f;
  float xr = (float)(j + CJ), yr = (float)(i + CI);
  float dx = xr - cx, dy = yr - cy;
  float rx = cx + P.cosT * dx + P.sinT * dy;
  float ry = cy - P.sinT * dx + P.cosT * dy;
  float x0f = floorf(rx), y0f = floorf(ry);
  int x0 = (int)x0f, y0 = (int)y0f;
  float wx1 = rx - x0f, wy1 = ry - y0f;
  float rwx[2] = {1.0f - wx1, wx1};
  float rwy[2] = {1.0f - wy1, wy1};
  int n = 0;
#pragma unroll
  for (int ny = 0; ny < 2; ++ny) {
#pragma unroll
    for (int nx = 0; nx < 2; ++nx) {
      int yn = y0 + ny, xn = x0 + nx;
      bool vn = (xn >= 0 && xn <= WW - 1 && yn >= 0 && yn <= HH - 1);
      float wn = rwy[ny] * rwx[nx] * (vn ? 1.0f : 0.0f);
      float xo = (float)xn, yo = (float)yn;
      float inv = 1.0f / (P.g * xo + P.h * yo + 1.0f);
      float px = (P.a * xo + P.b * yo + P.c) * inv;
      float py = (P.d * xo + P.e * yo + P.f) * inv;
      float px0f = floorf(px), py0f = floorf(py);
      int px0 = (int)px0f, py0 = (int)py0f;
      float pwx1 = px - px0f, pwy1 = py - py0f;
      float pwx[2] = {1.0f - pwx1, pwx1};
      float pwy[2] = {1.0f - pwy1, pwy1};
#pragma unroll
      for (int ty = 0; ty < 2; ++ty) {
#pragma unroll
        for (int tx = 0; tx < 2; ++tx) {
          int yt = py0 + ty, xt = px0 + tx;
          bool vt = (xt >= 0 && xt <= WW - 1 && yt >= 0 && yt <= HH - 1);
          wts[n * 4 + ty * 2 + tx] = wn * pwy[ty] * pwx[tx] * (vt ? 1.0f : 0.0f);
        }
      }
      int ly = py0 - by0;
      int lx = px0 - bx0;
      if (ly < -1 || ly > bh - 1) ly = 0;
      if (lx < -1 || lx > bw - 1) lx = 0;
      pofs[n] = (ly + 1) * LSTR + (lx + 1);
      ++n;
    }
  }
}

__global__ __launch_bounds__(256) void warp_direct_kernel(
    const float* __restrict__ xin, const float* __restrict__ nin,
    float* __restrict__ crop, AugParams P) {
  __shared__ float s_img[2][LWORDS];
  int tile = blockIdx.x;
  int ch0  = blockIdx.y * GCH;
  int i0 = (tile / NTIL) * TILE;
  int j0 = (tile % NTIL) * TILE;

  const float cx = (WW - 1) * 0.5f, cy = (HH - 1) * 0.5f;
  float rxmin = 1e30f, rxmax = -1e30f, rymin = 1e30f, rymax = -1e30f;
#pragma unroll
  for (int c = 0; c < 4; ++c) {
    float xr = (float)(j0 + CJ + ((c & 1) ? TILE - 1 : 0));
    float yr = (float)(i0 + CI + ((c & 2) ? TILE - 1 : 0));
    float dx = xr - cx, dy = yr - cy;
    float rx = cx + P.cosT * dx + P.sinT * dy;
    float ry = cy - P.sinT * dx + P.cosT * dy;
    rxmin = fminf(rxmin, rx); rxmax = fmaxf(rxmax, rx);
    rymin = fminf(rymin, ry); rymax = fmaxf(rymax, ry);
  }
  float xnlo = floorf(rxmin), xnhi = floorf(rxmax) + 1.0f;
  float ynlo = floorf(rymin), ynhi = floorf(rymax) + 1.0f;
  float pxmin = 1e30f, pxmax = -1e30f, pymin = 1e30f, pymax = -1e30f;
#pragma unroll
  for (int c = 0; c < 4; ++c) {
    float xo = (c & 1) ? xnhi : xnlo;
    float yo = (c & 2) ? ynhi : ynlo;
    float inv = 1.0f / (P.g * xo + P.h * yo + 1.0f);
    float px = (P.a * xo + P.b * yo + P.c) * inv;
    float py = (P.d * xo + P.e * yo + P.f) * inv;
    pxmin = fminf(pxmin, px); pxmax = fmaxf(pxmax, px);
    pymin = fminf(pymin, py); pymax = fmaxf(pymax, py);
  }
  int bx0 = max(0, (int)floorf(pxmin));
  int bx1 = min(WW - 1, (int)floorf(pxmax) + 1);
  int by0 = max(0, (int)floorf(pymin));
  int by1 = min(HH - 1, (int)floorf(pymax) + 1);
  int bw = bx1 - bx0 + 1;
  int bh = by1 - by0 + 1;
  bool use_lds = (bw <= BMAXW && bh <= BMAXH);

  int tid = threadIdx.x;
  int i = i0 + (tid >> 4);
  int j = j0 + (tid & 15);
  int opix = i * CROP + j;

  if (use_lds) {
    int pofs[4]; float wts[16];
    make_patches(i, j, P, by0, bx0, bh, bw, pofs, wts);
    for (int s = tid; s < 2 * LWORDS; s += 256)
      ((float*)s_img)[s] = 0.0f;
    __syncthreads();
    {
      const float* xb = xin + (size_t)ch0 * CH_STRIDE;
      const float* nb = nin + (size_t)ch0 * CH_STRIDE;
      int r = tid >> 5, c = tid & 31;
#pragma unroll
      for (int rr = 0; rr < 5; ++rr) {
        int rcur = r + rr * 8;
        if (rcur < bh && c < bw) {
          int g = (by0 + rcur) * WW + bx0 + c;
          s_img[0][(rcur + 1) * LSTR + (c + 1)] = preproc(xb[g], nb[g]);
        }
      }
      if (bw > 32) {
        int r2 = tid >> 2, c2 = 32 + (tid & 3);
        if (r2 < bh && c2 < bw) {
          int g = (by0 + r2) * WW + bx0 + c2;
          s_img[0][(r2 + 1) * LSTR + (c2 + 1)] = preproc(xb[g], nb[g]);
        }
      }
      __syncthreads();
    }
    int buf = 0;
    int r = tid >> 5, c = tid & 31;
    int r2 = tid >> 2, c2 = 32 + (tid & 3);
    for (int cc = 0; cc < GCH; ++cc) {
      int ch = ch0 + cc;
      bool more = (cc < GCH - 1);
      float xv[5], nv[5], xe = 0.0f, ne = 0.0f;
      if (more) {
        const float* xb = xin + (size_t)(ch + 1) * CH_STRIDE;
        const float* nb = nin + (size_t)(ch + 1) * CH_STRIDE;
#pragma unroll
        for (int rr = 0; rr < 5; ++rr) {
          int rcur = r + rr * 8;
          if (rcur < bh && c < bw) {
            int g = (by0 + rcur) * WW + bx0 + c;
            xv[rr] = xb[g]; nv[rr] = nb[g];
          }
        }
        if (bw > 32 && r2 < bh && c2 < bw) {
          int g = (by0 + r2) * WW + bx0 + c2;
          xe = xb[g]; ne = nb[g];
        }
      }
      const float* sb = s_img[buf];
      float acc = 0.0f;
#pragma unroll
      for (int n = 0; n < 4; ++n) {
        int p = pofs[n];
        acc = fmaf(wts[n * 4 + 0], sb[p], acc);
        acc = fmaf(wts[n * 4 + 1], sb[p + 1], acc);
        acc = fmaf(wts[n * 4 + 2], sb[p + LSTR], acc);
        acc = fmaf(wts[n * 4 + 3], sb[p + LSTR + 1], acc);
      }
      crop[(size_t)ch * CROP_STRIDE + opix] = acc;
      if (more) {
        float* sw = s_img[buf ^ 1];
#pragma unroll
        for (int rr = 0; rr < 5; ++rr) {
          int rcur = r + rr * 8;
          if (rcur < bh && c < bw)
            sw[(rcur + 1) * LSTR + (c + 1)] = preproc(xv[rr], nv[rr]);
        }
        if (bw > 32 && r2 < bh && c2 < bw)
          sw[(r2 + 1) * LSTR + (c2 + 1)] = preproc(xe, ne);
      }
      __syncthreads();
      buf ^= 1;
    }
  } else {
    int txs[16], tys[16]; float wts[16];
    make_taps(i, j, P, txs, tys, wts);
    for (int cc = 0; cc < GCH; ++cc) {
      int ch = ch0 + cc;
      const float* xb = xin + (size_t)ch * CH_STRIDE;
      const float* nb = nin + (size_t)ch * CH_STRIDE;
      float acc = 0.0f;
#pragma unroll
      for (int t = 0; t < 16; ++t) {
        int g = tys[t] * WW + txs[t];
        acc = fmaf(wts[t], preproc(xb[g], nb[g]), acc);
      }
      crop[(size_t)ch * CROP_STRIDE + opix] = acc;
    }
  }
}

// ---------------------------------------------------------------------------
// Kernel: separable bicubic 160->224, strip per (channel, 28 rows).
// Output stored non-temporally (never re-read) to preserve L2/L3 for inputs.
// ---------------------------------------------------------------------------
#define STRIPROWS 28
#define HROWS 25
__global__ __launch_bounds__(256) void resize_strips_kernel(
    const float* __restrict__ crop, const float4* __restrict__ wt,
    const int4* __restrict__ it, float* __restrict__ out) {
  __shared__ float hbuf[HROWS * WW];
  int s = blockIdx.x;
  int ch = blockIdx.y;
  int r0 = max(0, s * 20 - 2);
  const float* cb = crop + (size_t)ch * CROP_STRIDE;
  int tid = threadIdx.x;

  for (int e = tid; e < HROWS * WW; e += 256) {
    int r = e / WW;
    int xo = e - r * WW;
    int cr = min(r0 + r, CROP - 1);
    float4 wx = wt[xo]; int4 ix = it[xo];
    const float* row = cb + cr * CROP;
    hbuf[e] = wx.x * row[ix.x] + wx.y * row[ix.y] +
              wx.z * row[ix.z] + wx.w * row[ix.w];
  }
  __syncthreads();
  for (int e = tid; e < STRIPROWS * WW; e += 256) {
    int yl = e / WW;
    int xo = e - yl * WW;
    int yo = s * STRIPROWS + yl;
    float4 wy = wt[yo]; int4 iy = it[yo];
    float o = wy.x * hbuf[(iy.x - r0) * WW + xo] +
              wy.y * hbuf[(iy.y - r0) * WW + xo] +
              wy.z * hbuf[(iy.z - r0) * WW + xo] +
              wy.w * hbuf[(iy.w - r0) * WW + xo];
    __builtin_nontemporal_store(o, &out[((size_t)ch * HH + yo) * WW + xo]);
  }
}

// ---------------------------------------------------------------------------
// Fully fused fallback (tiny ws).
// ---------------------------------------------------------------------------
__device__ float crop_val(const float* __restrict__ xb, const float* __restrict__ nb,
                          int i, int j, AugParams P) {
  int txs[16], tys[16]; float wts[16];
  make_taps(i, j, P, txs, tys, wts);
  float acc = 0.0f;
#pragma unroll
  for (int t = 0; t < 16; ++t)
    acc = fmaf(wts[t], preproc(xb[tys[t] * WW + txs[t]], nb[tys[t] * WW + txs[t]]), acc);
  return acc;
}

__global__ __launch_bounds__(256) void fused_fallback_kernel(
    const float* __restrict__ xin, const float* __restrict__ nin,
    float* __restrict__ out, AugParams P, int total) {
  int stride = gridDim.x * blockDim.x;
  for (int idx = blockIdx.x * blockDim.x + threadIdx.x; idx < total; idx += stride) {
    int xo = idx % WW;
    int t2 = idx / WW;
    int yo = t2 % HH;
    int ch = t2 / HH;
    float wxa[4]; int ixa[4]; axis_weights(xo, wxa, ixa);
    float wya[4]; int iya[4]; axis_weights(yo, wya, iya);
    const float* xb = xin + (size_t)ch * CH_STRIDE;
    const float* nb = nin + (size_t)ch * CH_STRIDE;
    float acc = 0.0f;
#pragma unroll
    for (int ty = 0; ty < 4; ++ty)
#pragma unroll
      for (int tx = 0; tx < 4; ++tx)
        acc += wya[ty] * wxa[tx] * crop_val(xb, nb, iya[ty], ixa[tx], P);
    out[idx] = acc;
  }
}

// ---------------------------------------------------------------------------
// Host: solve 8x8 perspective system.
// ---------------------------------------------------------------------------
static void solve_coeffs(double C[8]) {
  const double sp[4][2] = {{0, 0}, {223, 0}, {223, 223}, {0, 223}};
  const double ep[4][2] = {{30, 20}, {200, 25}, {210, 200}, {15, 190}};
  double A[8][9];
  for (int k = 0; k < 4; ++k) {
    double xi = sp[k][0], yi = sp[k][1], xo = ep[k][0], yo = ep[k][1];
    double r0[9] = {xo, yo, 1, 0, 0, 0, -xo * xi, -yo * xi, xi};
    double r1[9] = {0, 0, 0, xo, yo, 1, -xo * yi, -yo * yi, yi};
    std::memcpy(A[2 * k], r0, sizeof r0);
    std::memcpy(A[2 * k + 1], r1, sizeof r1);
  }
  for (int col = 0; col < 8; ++col) {
    int piv = col;
    for (int r = col + 1; r < 8; ++r)
      if (std::fabs(A[r][col]) > std::fabs(A[piv][col])) piv = r;
    if (piv != col)
      for (int cc = 0; cc < 9; ++cc) { double t = A[col][cc]; A[col][cc] = A[piv][cc]; A[piv][cc] = t; }
    double p = A[col][col];
    for (int r = 0; r < 8; ++r) {
      if (r == col) continue;
      double fmul = A[r][col] / p;
      for (int cc = col; cc < 9; ++cc) A[r][cc] -= fmul * A[col][cc];
    }
  }
  for (int r = 0; r < 8; ++r) C[r] = A[r][8] / A[r][r];
}

extern "C" void kernel_launch(void* const* d_in, const int* in_sizes, int n_in,
                              void* d_out, int out_size, void* d_ws, size_t ws_size,
                              hipStream_t stream) {
  const float* xin = (const float*)d_in[0];
  const float* nin = (const float*)d_in[1];
  float* out = (float*)d_out;

  double C[8];
  solve_coeffs(C);
  AugParams P;
  P.a = (float)C[0]; P.b = (float)C[1]; P.c = (float)C[2]; P.d = (float)C[3];
  P.e = (float)C[4]; P.f = (float)C[5]; P.g = (float)C[6]; P.h = (float)C[7];
  double t = 10.0 * M_PI / 180.0;
  P.cosT = (float)std::cos(t);
  P.sinT = (float)std::sin(t);

  const int total = NCH * HH * WW;                 // 19,267,584
  const size_t PRE_BYTES = (size_t)NCH * CH_STRIDE * 2;      // 38,535,168
  const size_t CROP_BYTES = (size_t)NCH * CROP_STRIDE * 4;   // 39,321,600

  // full layout: [pre][256 slack][wt][it][crop]
  const size_t TBLW_OFF = PRE_BYTES + 256;
  const size_t TBLI_OFF = TBLW_OFF + 3584;
  const size_t CROPF_OFF = TBLI_OFF + 3584;
  const size_t need_full = CROPF_OFF + CROP_BYTES;
  // medium layout: [wt][it][crop]
  const size_t need_med = 8192 + CROP_BYTES;

  if (ws_size >= need_full) {
    unsigned short* pre = (unsigned short*)d_ws;
    float4* wt = (float4*)((char*)d_ws + TBLW_OFF);
    int4*   it = (int4*)((char*)d_ws + TBLI_OFF);
    float* crop = (float*)((char*)d_ws + CROPF_OFF);

    hipLaunchKernelGGL(table_kernel, dim3(1), dim3(256), 0, stream, wt, it);
    hipLaunchKernelGGL(preproc_kernel, dim3(total / 16 / 256), dim3(256), 0, stream,
                       (const float4*)xin, (const float4*)nin, (ushort4*)pre);
    dim3 g1(NTIL2 * NTIL2, NCH / GCH2);            // (25, 48)
    hipLaunchKernelGGL(warp_pre_kernel, g1, dim3(256), 0, stream, pre, crop, P);
    dim3 g2(HH / STRIPROWS, NCH);                  // (8, 384)
    hipLaunchKernelGGL(resize_strips_kernel, g2, dim3(256), 0, stream, crop, wt, it, out);
  } else if (ws_size >= need_med) {
    float4* wt = (float4*)d_ws;
    int4*   it = (int4*)((char*)d_ws + 3584);
    float* crop = (float*)((char*)d_ws + 8192);

    hipLaunchKernelGGL(table_kernel, dim3(1), dim3(256), 0, stream, wt, it);
    dim3 g1(NTIL * NTIL, NCH / GCH);               // (100, 48)
    hipLaunchKernelGGL(warp_direct_kernel, g1, dim3(256), 0, stream, xin, nin, crop, P);
    dim3 g2(HH / STRIPROWS, NCH);
    hipLaunchKernelGGL(resize_strips_kernel, g2, dim3(256), 0, stream, crop, wt, it, out);
  } else {
    hipLaunchKernelGGL(fused_fallback_kernel, dim3(2048), dim3(256), 0, stream,
                       xin, nin, out, P, total);
  }
}